// Round 14
// baseline (526.840 us; speedup 1.0000x reference)
//
#include <hip/hip_runtime.h>
#include <hip/hip_bf16.h>

typedef __attribute__((ext_vector_type(4))) float f32x4;
typedef __attribute__((ext_vector_type(8))) short s16x8;

#define BSZ 128
#define TGT 197
#define EDIM 768
#define NH 12
#define HD 64
#define NF 16
#define M_TOT (BSZ*TGT)      // 25216
#define QKV_N (3*EDIM)       // 2304
#define KG (NF*TGT)          // 3152
#define VSTR 264
#define NSPL 8
#define KSPL 394
#define LSTR 424

__device__ __forceinline__ float b2f(unsigned short u) {
  return __uint_as_float(((unsigned int)u) << 16);
}
__device__ __forceinline__ float bf2f(__hip_bfloat16 b) { return __bfloat162float(b); }
__device__ __forceinline__ __hip_bfloat16 f2bf(float f) { return __float2bfloat16(f); }
__device__ __forceinline__ unsigned int packbf(float a, float b) {
  __hip_bfloat16 x = __float2bfloat16(a), y = __float2bfloat16(b);
  return (unsigned int)*(unsigned short*)&x | ((unsigned int)*(unsigned short*)&y << 16);
}
__device__ __forceinline__ int swz(int t, int c) {
  return t*64 + (c ^ ((((t & 7) ^ ((t >> 3) & 3))) << 3));
}
__device__ __forceinline__ int vswz(int d, int t) {
  return d*VSTR + (t ^ (d & 56));
}

__device__ __forceinline__ void gload_lds16(const void* gsrc, void* ldst) {
  __builtin_amdgcn_global_load_lds(
      (const __attribute__((address_space(1))) unsigned int*)gsrc,
      (__attribute__((address_space(3))) unsigned int*)ldst, 16, 0, 0);
}

// ---------------- batched convert descriptor (7 small weight tensors) ----------------
struct CvBatch {
  const void* src[7];
  void* dst[7];
  int off8[8];
};

// ---------------- prep: dtype detect + mask-zero scan + all converts ----------------
__global__ __launch_bounds__(256) void prep(
    const void* __restrict__ xsrc, const void* __restrict__ msrc,
    __hip_bfloat16* __restrict__ x_c, __hip_bfloat16* __restrict__ mask_c,
    CvBatch cb, int* __restrict__ flag, unsigned int* __restrict__ mznz)
{
  __shared__ float smax[256];
  const int tid = threadIdx.x;
  const unsigned short* xs = (const unsigned short*)xsrc;
  float mx = 0.f;
  for (int j = tid; j < 1024; j += 256) {
    float v = fabsf(b2f(xs[j]));
    mx = (v < 1e30f) ? fmaxf(mx, v) : 1e30f;
  }
  smax[tid] = mx;
  __syncthreads();
  if (tid == 0) {
    float m = 0.f;
    for (int j = 0; j < 256; ++j) m = fmaxf(m, smax[j]);
    smax[0] = (m < 100.f) ? 1.f : 0.f;
    if (blockIdx.x == 0) *flag = (m < 100.f) ? 1 : 0;
  }
  __syncthreads();
  const int isbf = (int)smax[0];

  const int gsz = gridDim.x * 256;
  const int gi = blockIdx.x * 256 + tid;

  {
    const unsigned int* mw = (const unsigned int*)msrc;
    const int nwords = isbf ? (4967552/2) : 4967552;
    const unsigned int am = isbf ? 0x7fff7fffu : 0x7fffffffu;
    unsigned int acc = 0;
    for (int i = gi; i < nwords; i += gsz) acc |= (mw[i] & am);
    if (acc) atomicOr(mznz, 1u);
  }

  {
    const int total = cb.off8[7];
    for (int i = gi; i < total; i += gsz) {
      int s = 0;
      #pragma unroll
      for (int k = 1; k < 7; ++k) s += (i >= cb.off8[k]);
      const int li = i - cb.off8[s];
      if (isbf) {
        ((s16x8*)cb.dst[s])[li] = ((const s16x8*)cb.src[s])[li];
      } else {
        const f32x4* sp = (const f32x4*)cb.src[s];
        f32x4 a = sp[li*2], b = sp[li*2+1];
        s16x8 o;
        #pragma unroll
        for (int j = 0; j < 4; ++j) { __hip_bfloat16 t = f2bf(a[j]); o[j] = *(short*)&t; }
        #pragma unroll
        for (int j = 0; j < 4; ++j) { __hip_bfloat16 t = f2bf(b[j]); o[4+j] = *(short*)&t; }
        ((s16x8*)cb.dst[s])[li] = o;
      }
    }
  }

  if (!isbf) {
    {
      const f32x4* s = (const f32x4*)xsrc;
      s16x8* d = (s16x8*)x_c;
      for (int i = gi; i < 19365888/8; i += gsz) {
        f32x4 a = s[i*2], b = s[i*2+1];
        s16x8 o;
        #pragma unroll
        for (int j = 0; j < 4; ++j) { __hip_bfloat16 t = f2bf(a[j]); o[j] = *(short*)&t; }
        #pragma unroll
        for (int j = 0; j < 4; ++j) { __hip_bfloat16 t = f2bf(b[j]); o[4+j] = *(short*)&t; }
        d[i] = o;
      }
    }
    {
      const f32x4* s = (const f32x4*)msrc;
      s16x8* d = (s16x8*)mask_c;
      for (int i = gi; i < 4967552/8; i += gsz) {
        f32x4 a = s[i*2], b = s[i*2+1];
        s16x8 o;
        #pragma unroll
        for (int j = 0; j < 4; ++j) { __hip_bfloat16 t = f2bf(a[j]); o[j] = *(short*)&t; }
        #pragma unroll
        for (int j = 0; j < 4; ++j) { __hip_bfloat16 t = f2bf(b[j]); o[4+j] = *(short*)&t; }
        d[i] = o;
      }
    }
  }
}

// ---------------- Wc = in_proj_weight + lora_b @ lora_a ----------------
__global__ __launch_bounds__(256) void build_wc(
    const void* __restrict__ W,
    const void* __restrict__ la,
    const void* __restrict__ lb,
    __hip_bfloat16* __restrict__ Wc,
    const int* __restrict__ flag)
{
  __shared__ float lbr[64];
  const int isbf = *flag;
  const int n = blockIdx.x;
  if (threadIdx.x < 64)
    lbr[threadIdx.x] = isbf ? bf2f(((const __hip_bfloat16*)lb)[n*64 + threadIdx.x])
                            : ((const float*)lb)[n*64 + threadIdx.x];
  __syncthreads();
  if (isbf) {
    const __hip_bfloat16* Wb = (const __hip_bfloat16*)W;
    const __hip_bfloat16* lab = (const __hip_bfloat16*)la;
    for (int e = threadIdx.x; e < EDIM; e += 256) {
      float acc = bf2f(Wb[(size_t)n*EDIM + e]);
      for (int r = 0; r < 64; ++r) acc += lbr[r] * bf2f(lab[r*EDIM + e]);
      Wc[(size_t)n*EDIM + e] = f2bf(acc);
    }
  } else {
    const float* Wf = (const float*)W;
    const float* laf = (const float*)la;
    for (int e = threadIdx.x; e < EDIM; e += 256) {
      float acc = Wf[(size_t)n*EDIM + e];
      for (int r = 0; r < 64; ++r) acc += lbr[r] * laf[r*EDIM + e];
      Wc[(size_t)n*EDIM + e] = f2bf(acc);
    }
  }
}

// ---------------- 256x256 8-phase GEMM (round-8 spread-prefetch schedule) ----------------
__global__ __launch_bounds__(512) void gemm_bt_8ph(
    const __hip_bfloat16* __restrict__ A,
    const __hip_bfloat16* __restrict__ A_alt,
    const __hip_bfloat16* __restrict__ B,
    const __hip_bfloat16* __restrict__ bias,
    void* __restrict__ C,
    int M, int N, int K, int ntiles,
    const int* __restrict__ flag, int flag_mode)
{
  __shared__ char lds[131072];
  const int tid = threadIdx.x;
  const int wave = tid >> 6, lane = tid & 63;
  const int l16 = lane & 15, kq = lane >> 4;
  const int wr = wave >> 2, wc2 = wave & 3;

  const int nwg = gridDim.x;
  const int bid = blockIdx.x;
  const int qc = nwg >> 3, rc = nwg & 7;
  const int xcd = bid & 7;
  const int wgid = (xcd < rc ? xcd*(qc+1) : rc*(qc+1) + (xcd-rc)*qc) + (bid >> 3);
  const long brow = (long)(wgid / ntiles) * 256;
  const long bcol = (long)(wgid % ntiles) * 256;

  const int isbf = *flag;
  const __hip_bfloat16* Ause = isbf ? A_alt : A;
  const int nkt = K >> 6;

  const int srow = tid >> 3;
  const int schunk = tid & 7;
  const int wuni = wave << 10;

  auto stA = [&](int t, int buf, int issue) {
    int ar = issue*64 + srow;
    int cs = schunk ^ (ar & 7);
    long gr = brow + ar; if (gr > (long)M - 1) gr = M - 1;
    gload_lds16(Ause + gr*(long)K + t*64 + cs*8,
                lds + buf*65536 + issue*8192 + wuni);
  };
  auto stB = [&](int t, int buf, int issue) {
    int br = issue*64 + srow;
    int cs = schunk ^ (br & 7);
    gload_lds16(B + (bcol + br)*(long)K + t*64 + cs*8,
                lds + buf*65536 + 32768 + issue*8192 + wuni);
  };
  auto rdA = [&](int buf, int q, int a, int ks) -> s16x8 {
    int ar = wr*128 + q*32 + a*16 + l16;
    int ch = ks*4 + kq;
    return *(const s16x8*)(lds + buf*65536 + ar*128 + ((ch ^ (ar & 7)) << 4));
  };
  auto rdB = [&](int buf, int ni, int ks) -> s16x8 {
    int br = wc2*64 + ni*16 + l16;
    int ch = ks*4 + kq;
    return *(const s16x8*)(lds + buf*65536 + 32768 + br*128 + ((ch ^ (br & 7)) << 4));
  };

  f32x4 acc[8][4];
  #pragma unroll
  for (int i = 0; i < 8; ++i)
    #pragma unroll
    for (int j = 0; j < 4; ++j) acc[i][j] = (f32x4){0.f,0.f,0.f,0.f};

  stB(0,0,0); stB(0,0,1); stB(0,0,2); stB(0,0,3);
  stA(0,0,0); stA(0,0,2); stA(0,0,1); stA(0,0,3);
  asm volatile("s_waitcnt vmcnt(2)" ::: "memory");
  __builtin_amdgcn_s_barrier();

  for (int t = 0; t < nkt; ++t) {
    const int cur = t & 1, nxt = cur ^ 1;
    const bool pf = (t + 1 < nkt);
    s16x8 bfr[4][2], af[2][2];

    #pragma unroll
    for (int ni = 0; ni < 4; ++ni) { bfr[ni][0] = rdB(cur,ni,0); bfr[ni][1] = rdB(cur,ni,1); }
    af[0][0]=rdA(cur,0,0,0); af[0][1]=rdA(cur,0,0,1);
    af[1][0]=rdA(cur,0,1,0); af[1][1]=rdA(cur,0,1,1);
    if (pf) { stB(t+1,nxt,0); stB(t+1,nxt,1); }
    __builtin_amdgcn_s_barrier();
    asm volatile("s_waitcnt lgkmcnt(0)" ::: "memory");
    __builtin_amdgcn_sched_barrier(0);
    __builtin_amdgcn_s_setprio(1);
    #pragma unroll
    for (int ks = 0; ks < 2; ++ks)
      #pragma unroll
      for (int ni = 0; ni < 4; ++ni) {
        acc[0][ni] = __builtin_amdgcn_mfma_f32_16x16x32_bf16(af[0][ks], bfr[ni][ks], acc[0][ni], 0,0,0);
        acc[1][ni] = __builtin_amdgcn_mfma_f32_16x16x32_bf16(af[1][ks], bfr[ni][ks], acc[1][ni], 0,0,0);
      }
    __builtin_amdgcn_s_setprio(0);

    af[0][0]=rdA(cur,1,0,0); af[0][1]=rdA(cur,1,0,1);
    af[1][0]=rdA(cur,1,1,0); af[1][1]=rdA(cur,1,1,1);
    if (pf) {
      stB(t+1,nxt,2); stB(t+1,nxt,3);
      asm volatile("s_waitcnt vmcnt(4)" ::: "memory");
    } else {
      asm volatile("s_waitcnt vmcnt(0)" ::: "memory");
    }
    __builtin_amdgcn_s_barrier();
    asm volatile("s_waitcnt lgkmcnt(0)" ::: "memory");
    __builtin_amdgcn_sched_barrier(0);
    __builtin_amdgcn_s_setprio(1);
    #pragma unroll
    for (int ks = 0; ks < 2; ++ks)
      #pragma unroll
      for (int ni = 0; ni < 4; ++ni) {
        acc[2][ni] = __builtin_amdgcn_mfma_f32_16x16x32_bf16(af[0][ks], bfr[ni][ks], acc[2][ni], 0,0,0);
        acc[3][ni] = __builtin_amdgcn_mfma_f32_16x16x32_bf16(af[1][ks], bfr[ni][ks], acc[3][ni], 0,0,0);
      }
    __builtin_amdgcn_s_setprio(0);

    af[0][0]=rdA(cur,2,0,0); af[0][1]=rdA(cur,2,0,1);
    af[1][0]=rdA(cur,2,1,0); af[1][1]=rdA(cur,2,1,1);
    if (pf) { stA(t+1,nxt,0); stA(t+1,nxt,2); }
    __builtin_amdgcn_s_barrier();
    asm volatile("s_waitcnt lgkmcnt(0)" ::: "memory");
    __builtin_amdgcn_sched_barrier(0);
    __builtin_amdgcn_s_setprio(1);
    #pragma unroll
    for (int ks = 0; ks < 2; ++ks)
      #pragma unroll
      for (int ni = 0; ni < 4; ++ni) {
        acc[4][ni] = __builtin_amdgcn_mfma_f32_16x16x32_bf16(af[0][ks], bfr[ni][ks], acc[4][ni], 0,0,0);
        acc[5][ni] = __builtin_amdgcn_mfma_f32_16x16x32_bf16(af[1][ks], bfr[ni][ks], acc[5][ni], 0,0,0);
      }
    __builtin_amdgcn_s_setprio(0);

    af[0][0]=rdA(cur,3,0,0); af[0][1]=rdA(cur,3,0,1);
    af[1][0]=rdA(cur,3,1,0); af[1][1]=rdA(cur,3,1,1);
    if (pf) { stA(t+1,nxt,1); stA(t+1,nxt,3); }
    asm volatile("s_waitcnt vmcnt(2)" ::: "memory");
    __builtin_amdgcn_s_barrier();
    asm volatile("s_waitcnt lgkmcnt(0)" ::: "memory");
    __builtin_amdgcn_sched_barrier(0);
    __builtin_amdgcn_s_setprio(1);
    #pragma unroll
    for (int ks = 0; ks < 2; ++ks)
      #pragma unroll
      for (int ni = 0; ni < 4; ++ni) {
        acc[6][ni] = __builtin_amdgcn_mfma_f32_16x16x32_bf16(af[0][ks], bfr[ni][ks], acc[6][ni], 0,0,0);
        acc[7][ni] = __builtin_amdgcn_mfma_f32_16x16x32_bf16(af[1][ks], bfr[ni][ks], acc[7][ni], 0,0,0);
      }
    __builtin_amdgcn_s_setprio(0);
  }

  __builtin_amdgcn_s_barrier();

  const int f32o = flag_mode && (!isbf);
  float bv[4];
  #pragma unroll
  for (int ni = 0; ni < 4; ++ni) bv[ni] = bf2f(bias[bcol + wc2*64 + ni*16 + l16]);
  const int o4 = kq*4;

  if (!f32o) {
    __hip_bfloat16* eb = (__hip_bfloat16*)(lds + wave*2048);
    __hip_bfloat16* Cb = (__hip_bfloat16*)C;
    const int rr = lane >> 3, cg = lane & 7;
    #pragma unroll
    for (int mi = 0; mi < 8; ++mi) {
      #pragma unroll
      for (int ni = 0; ni < 4; ++ni)
        #pragma unroll
        for (int r = 0; r < 4; ++r) {
          const int row16 = o4 + r;
          const int sidx = row16*64 + ((((ni*2 + (l16 >> 3)) ^ (row16 & 7)) << 3) | (l16 & 7));
          eb[sidx] = f2bf(acc[mi][ni][r] + bv[ni]);
        }
      asm volatile("s_waitcnt lgkmcnt(0)" ::: "memory");
      __builtin_amdgcn_sched_barrier(0);
      #pragma unroll
      for (int pass = 0; pass < 2; ++pass) {
        const int row16 = pass*8 + rr;
        const long grow = brow + wr*128 + mi*16 + row16;
        if (grow < M) {
          s16x8 v = *(const s16x8*)(eb + row16*64 + ((cg ^ (row16 & 7)) << 3));
          *(s16x8*)(Cb + grow*(long)N + bcol + wc2*64 + cg*8) = v;
        }
      }
      asm volatile("s_waitcnt lgkmcnt(0)" ::: "memory");
      __builtin_amdgcn_sched_barrier(0);
    }
  } else {
    #pragma unroll
    for (int mi = 0; mi < 8; ++mi)
      #pragma unroll
      for (int ni = 0; ni < 4; ++ni)
        #pragma unroll
        for (int r = 0; r < 4; ++r) {
          const long grow = brow + wr*128 + mi*16 + o4 + r;
          if (grow < M)
            ((float*)C)[grow*(long)N + bcol + wc2*64 + ni*16 + l16] = acc[mi][ni][r] + bv[ni];
        }
  }
}

// ---------------- fused attention: V^T-only LDS, K direct from global ----------------
__global__ __launch_bounds__(256) void attn_fused(
    const __hip_bfloat16* __restrict__ qkv,
    const __hip_bfloat16* __restrict__ mask,
    const __hip_bfloat16* __restrict__ mask_raw,
    const int* __restrict__ flag,
    const unsigned int* __restrict__ mzp,
    __hip_bfloat16* __restrict__ xop)
{
  __shared__ __hip_bfloat16 lVt[64*VSTR];

  const int tid = threadIdx.x;
  const int blk = blockIdx.x;
  const int xcd = blk & 7;
  const int slot = blk >> 3;
  const int ih = xcd * 192 + (slot >> 2);
  const int qt = slot & 3;
  const int h = ih % NH;
  const int i = ih / NH;
  const int q0 = qt * 64;
  const size_t rowbase = (size_t)i * TGT;
  const int wave = tid >> 6, lane = tid & 63;
  const int l16 = lane & 15, kq = lane >> 4;
  const int mz = (*mzp == 0u);
  const __hip_bfloat16* msk = (*flag) ? mask_raw : mask;

  int qr = q0 + wave*16 + l16;
  const int qrc = qr > TGT-1 ? TGT-1 : qr;
  s16x8 qf[2];
  #pragma unroll
  for (int kk = 0; kk < 2; ++kk)
    qf[kk] = *(const s16x8*)(qkv + (rowbase + qrc)*QKV_N + h*HD + kk*32 + kq*8);

  const f32x4 z = {0.f,0.f,0.f,0.f};
  for (int idx = tid; idx < 224*8; idx += 256) {
    int t = idx >> 3, c8 = idx & 7;
    f32x4 vv = z;
    if (t < TGT) vv = *(const f32x4*)(qkv + (rowbase + t)*QKV_N + 2*EDIM + h*HD + c8*8);
    const __hip_bfloat16* pv = (const __hip_bfloat16*)&vv;
    const int tx = t ^ (c8 << 3);
    #pragma unroll
    for (int j = 0; j < 8; ++j)
      lVt[(c8*8 + j)*VSTR + tx] = pv[j];
  }
  __syncthreads();

  f32x4 acc[14];
  #pragma unroll
  for (int nf = 0; nf < 14; ++nf) {
    int trow = nf*16 + l16; if (trow > TGT-1) trow = TGT-1;
    acc[nf] = (f32x4){0.f,0.f,0.f,0.f};
    #pragma unroll
    for (int kk = 0; kk < 2; ++kk) {
      s16x8 kf = *(const s16x8*)(qkv + (rowbase + trow)*QKV_N + EDIM + h*HD + kk*32 + kq*8);
      acc[nf] = __builtin_amdgcn_mfma_f32_16x16x32_bf16(kf, qf[kk], acc[nf], 0, 0, 0);
    }
  }

  float mx = -1e30f;
  #pragma unroll
  for (int nf = 0; nf < 14; ++nf) {
    #pragma unroll
    for (int r = 0; r < 4; ++r) {
      const int t = nf*16 + kq*4 + r;
      float s;
      if (t < TGT) {
        s = acc[nf][r]*0.125f;
        if (!mz) s += bf2f(msk[(rowbase + qrc)*TGT + t]);
      } else s = -1e30f;
      acc[nf][r] = s;
      mx = fmaxf(mx, s);
    }
  }
  mx = fmaxf(mx, __shfl_xor(mx, 16));
  mx = fmaxf(mx, __shfl_xor(mx, 32));

  float rs = 0.f;
  unsigned int pk[14][2];
  #pragma unroll
  for (int nf = 0; nf < 14; ++nf) {
    float p0 = __expf(acc[nf][0] - mx);
    float p1 = __expf(acc[nf][1] - mx);
    float p2 = __expf(acc[nf][2] - mx);
    float p3 = __expf(acc[nf][3] - mx);
    rs += (p0 + p1) + (p2 + p3);
    pk[nf][0] = packbf(p0, p1);
    pk[nf][1] = packbf(p2, p3);
  }
  rs += __shfl_xor(rs, 16);
  rs += __shfl_xor(rs, 32);

  f32x4 oacc[4];
  #pragma unroll
  for (int nf = 0; nf < 4; ++nf) oacc[nf] = (f32x4){0.f,0.f,0.f,0.f};

  const int slbase = l16 + ((kq & 1) << 5);
  #pragma unroll
  for (int kt = 0; kt < 7; ++kt) {
    s16x8 pa;
    #pragma unroll
    for (int jp = 0; jp < 4; ++jp) {
      const int srcLane = slbase + ((jp >> 1) << 4);
      int va = __shfl((int)pk[2*kt][jp & 1], srcLane, 64);
      int vb = __shfl((int)pk[2*kt + 1][jp & 1], srcLane, 64);
      int sel = (kq < 2) ? va : vb;
      pa[2*jp]     = (short)(sel & 0xffff);
      pa[2*jp + 1] = (short)(((unsigned int)sel) >> 16);
    }
    #pragma unroll
    for (int nf = 0; nf < 4; ++nf) {
      s16x8 vf = *(const s16x8*)(lVt + vswz(nf*16 + l16, kt*32 + kq*8));
      oacc[nf] = __builtin_amdgcn_mfma_f32_16x16x32_bf16(pa, vf, oacc[nf], 0, 0, 0);
    }
  }

  #pragma unroll
  for (int r = 0; r < 4; ++r) {
    const float rsrc = __shfl(rs, kq*4 + r, 64);
    const int qw = q0 + wave*16 + kq*4 + r;
    if (qw < TGT) {
      const float inv = 1.0f / rsrc;
      #pragma unroll
      for (int nf = 0; nf < 4; ++nf)
        xop[(rowbase + qw)*(size_t)EDIM + h*HD + nf*16 + l16] = f2bf(oacc[nf][r] * inv);
    }
  }
}

// ---------------- CLS split-K attention ----------------
__global__ __launch_bounds__(256) void cls_split(
    const __hip_bfloat16* __restrict__ qkv,
    const __hip_bfloat16* __restrict__ mask,
    const __hip_bfloat16* __restrict__ mask_raw,
    const int* __restrict__ flag,
    const unsigned int* __restrict__ mzp,
    const int* __restrict__ top_idx,
    float* __restrict__ pO,
    float* __restrict__ pm,
    float* __restrict__ pl)
{
  __shared__ __hip_bfloat16 lQ[16*64];
  __shared__ __hip_bfloat16 lS[16*LSTR];
  __shared__ __hip_bfloat16 lV[256*64];
  __shared__ float red[16][17];
  __shared__ float rmax[16];
  __shared__ float rsum[16];

  const int tid = threadIdx.x;
  const int sp = blockIdx.x & 7;
  const int gh = blockIdx.x >> 3;
  const int g = gh / NH;
  const int h = gh % NH;
  const int k0 = sp * KSPL;
  const int wave = tid >> 6, lane = tid & 63;
  const int l16 = lane & 15, kq = lane >> 4, o4 = (lane >> 4) * 4;
  const int mz = (*mzp == 0u);
  const __hip_bfloat16* msk = (*flag) ? mask_raw : mask;

  if (tid < 128) {
    int qi = tid >> 3, c8 = tid & 7;
    int ib = g*NF + qi;
    int top = top_idx[ib];
    f32x4 v = *(const f32x4*)(qkv + ((size_t)ib*TGT + top)*QKV_N + h*HD + c8*8);
    *(f32x4*)(lQ + qi*64 + c8*8) = v;
  }
  __syncthreads();

  s16x8 q8[2];
  #pragma unroll
  for (int kk = 0; kk < 2; ++kk)
    q8[kk] = *(const s16x8*)(lQ + l16*64 + kk*32 + kq*8);

  for (int nf = wave; nf < 26; nf += 4) {
    const int keyl = nf*16 + l16;
    const int keyg = k0 + (keyl < KSPL ? keyl : 0);
    f32x4 a = {0.f,0.f,0.f,0.f};
    const size_t krow = (size_t)g*KG + keyg;
    #pragma unroll
    for (int kk = 0; kk < 2; ++kk) {
      s16x8 k8 = *(const s16x8*)(qkv + krow*QKV_N + EDIM + h*HD + kk*32 + kq*8);
      a = __builtin_amdgcn_mfma_f32_16x16x32_bf16(q8[kk], k8, a, 0, 0, 0);
    }
    float mval = 0.f;
    if (!mz && keyl < KSPL) {
      const int f = keyg / 197;
      const int t = keyg - f*197;
      mval = bf2f(msk[((size_t)(g*NF + f)*TGT + (TGT-1))*TGT + t]);
    }
    #pragma unroll
    for (int r = 0; r < 4; ++r)
      lS[(o4 + r)*LSTR + nf*16 + l16] = f2bf(keyl < KSPL ? a[r]*0.125f + mval : -1e30f);
  }
  __syncthreads();

  {
    const int q = tid >> 4, c = tid & 15;
    float mx = -1e30f;
    for (int gch = c; gch < 52; gch += 16) {
      s16x8 sv = *(const s16x8*)(lS + q*LSTR + gch*8);
      #pragma unroll
      for (int j = 0; j < 8; ++j) mx = fmaxf(mx, b2f((unsigned short)sv[j]));
    }
    red[q][c] = mx;
    __syncthreads();
    if (tid < 16) {
      float m = red[tid][0];
      for (int j = 1; j < 16; ++j) m = fmaxf(m, red[tid][j]);
      rmax[tid] = m;
    }
    __syncthreads();
    const float rowmax = rmax[q];
    float sum = 0.f;
    for (int gch = c; gch < 52; gch += 16) {
      s16x8 sv = *(const s16x8*)(lS + q*LSTR + gch*8);
      s16x8 ov;
      #pragma unroll
      for (int jp = 0; jp < 4; ++jp) {
        float e0 = __expf(b2f((unsigned short)sv[2*jp])   - rowmax);
        float e1 = __expf(b2f((unsigned short)sv[2*jp+1]) - rowmax);
        sum += e0 + e1;
        unsigned int pr = packbf(e0, e1);
        ov[2*jp]   = (short)(pr & 0xffff);
        ov[2*jp+1] = (short)(pr >> 16);
      }
      *(s16x8*)(lS + q*LSTR + gch*8) = ov;
    }
    red[q][c] = sum;
    __syncthreads();
    if (tid < 16) {
      float s = 0.f;
      for (int j = 0; j < 16; ++j) s += red[tid][j];
      rsum[tid] = s;
    }
  }

  f32x4 oa = {0.f,0.f,0.f,0.f};
  const f32x4 z = {0.f,0.f,0.f,0.f};
  #pragma unroll
  for (int cki = 0; cki < 2; ++cki) {
    const int ck = cki * 256;
    const int nrows = cki ? 160 : 256;
    const int nks = cki ? 5 : 8;
    __syncthreads();
    for (int idx = tid; idx < nrows*8; idx += 256) {
      int t2 = idx >> 3, c8 = idx & 7;
      int keyl = ck + t2;
      f32x4 v = z;
      if (keyl < KSPL)
        v = *(const f32x4*)(qkv + ((size_t)g*KG + k0 + keyl)*QKV_N + 2*EDIM + h*HD + c8*8);
      *(f32x4*)(lV + swz(t2, c8*8)) = v;
    }
    __syncthreads();
    for (int ks = 0; ks < nks; ++ks) {
      s16x8 pa = *(const s16x8*)(lS + l16*LSTR + ck + ks*32 + kq*8);
      s16x8 vf;
      #pragma unroll
      for (int j = 0; j < 8; ++j) {
        const int t2 = ks*32 + kq*8 + j;
        vf[j] = *(const short*)(lV + swz(t2, wave*16 + l16));
      }
      oa = __builtin_amdgcn_mfma_f32_16x16x32_bf16(pa, vf, oa, 0, 0, 0);
    }
  }

  const int ps = gh*NSPL + sp;
  #pragma unroll
  for (int r = 0; r < 4; ++r)
    pO[((size_t)ps*16 + (o4 + r))*64 + wave*16 + l16] = oa[r];
  if (tid < 16) {
    pm[ps*16 + tid] = rmax[tid];
    pl[ps*16 + tid] = rsum[tid];
  }
}

// ---------------- final: combine CLS partials + out-proj dot + LoRA head + row update
__global__ __launch_bounds__(256) void final_cls(
    void* __restrict__ out,
    const float* __restrict__ pO,
    const float* __restrict__ pm,
    const float* __restrict__ pl,
    const __hip_bfloat16* __restrict__ wOut,
    const __hip_bfloat16* __restrict__ bOut,
    const __hip_bfloat16* __restrict__ dw, const __hip_bfloat16* __restrict__ db,
    const __hip_bfloat16* __restrict__ uw, const __hip_bfloat16* __restrict__ ub,
    const int* __restrict__ top_idx, const int* __restrict__ flag)
{
  __shared__ float xr[EDIM];    // combined (unprojected) x_1 row for batch i
  __shared__ float x0[EDIM];    // current d_out row (out-proj'd attention)
  __shared__ float hmid[64];
  const int i = blockIdx.x;
  const int tid = threadIdx.x;
  const int q = i & (NF - 1);
  const int g = i >> 4;
  const int top = top_idx[i];
  const int isbf = *flag;
  const size_t rowoff = ((size_t)i*TGT + top)*EDIM;

  // 1) inline split-K combine: xr[h*64+d]
  for (int e = tid; e < EDIM; e += 256) {
    const int h = e >> 6, d = e & 63;
    const int gh = g*NH + h;
    float M = -1e30f;
    #pragma unroll
    for (int s = 0; s < NSPL; ++s) M = fmaxf(M, pm[(gh*NSPL + s)*16 + q]);
    float L = 0.f, acc = 0.f;
    #pragma unroll
    for (int s = 0; s < NSPL; ++s) {
      const float sc = __expf(pm[(gh*NSPL + s)*16 + q] - M);
      L += pl[(gh*NSPL + s)*16 + q] * sc;
      acc += pO[((size_t)(gh*NSPL + s)*16 + q)*64 + d] * sc;
    }
    xr[e] = acc / L;
  }
  // 2) read current output row
  for (int e = tid; e < EDIM; e += 256)
    x0[e] = isbf ? bf2f(((const __hip_bfloat16*)out)[rowoff + e])
                 : ((const float*)out)[rowoff + e];
  __syncthreads();

  // 3) LoRA down + quick_gelu
  if (tid < 64) {
    float a = bf2f(db[tid]);
    for (int e = 0; e < EDIM; ++e) a += x0[e] * bf2f(dw[tid*EDIM + e]);
    hmid[tid] = a / (1.f + __expf(-1.702f * a));
  }
  __syncthreads();

  // 4) x_1 out-proj dot + LoRA up + write
  for (int e = tid; e < EDIM; e += 256) {
    float a = bf2f(bOut[e]);
    const __hip_bfloat16* wrow = wOut + (size_t)e*EDIM;
    for (int k8 = 0; k8 < EDIM/8; ++k8) {
      s16x8 w = *(const s16x8*)(wrow + k8*8);
      #pragma unroll
      for (int j = 0; j < 8; ++j) a += xr[k8*8 + j] * b2f((unsigned short)w[j]);
    }
    a += bf2f(ub[e]);
    #pragma unroll
    for (int r = 0; r < 64; ++r) a += hmid[r] * bf2f(uw[e*64 + r]);
    if (isbf) ((__hip_bfloat16*)out)[rowoff + e] = f2bf(a);
    else ((float*)out)[rowoff + e] = a;
  }
}

extern "C" void kernel_launch(void* const* d_in, const int* in_sizes, int n_in,
                              void* d_out, int out_size, void* d_ws, size_t ws_size,
                              hipStream_t stream) {
  (void)in_sizes; (void)n_in; (void)out_size; (void)ws_size;
  const int* top_idx = (const int*)d_in[13];
  const __hip_bfloat16* x_raw    = (const __hip_bfloat16*)d_in[0];
  const __hip_bfloat16* mask_raw = (const __hip_bfloat16*)d_in[1];

  char* ws = (char*)d_ws;
  size_t off = 0;
  auto alloc = [&](size_t bytes) { char* p = ws + off; off += (bytes + 15) & ~(size_t)15; return p; };

  int* flag = (int*)alloc(16);
  unsigned int* mznz = (unsigned int*)alloc(16);
  __hip_bfloat16* x_c    = (__hip_bfloat16*)alloc((size_t)19365888*2);
  __hip_bfloat16* mask_c = (__hip_bfloat16*)alloc((size_t)4967552*2);
  __hip_bfloat16* bIn_c  = (__hip_bfloat16*)alloc((size_t)2304*2);
  __hip_bfloat16* wOut_c = (__hip_bfloat16*)alloc((size_t)589824*2);
  __hip_bfloat16* bOut_c = (__hip_bfloat16*)alloc((size_t)768*2);
  __hip_bfloat16* dw_c   = (__hip_bfloat16*)alloc((size_t)49152*2);
  __hip_bfloat16* db_c   = (__hip_bfloat16*)alloc((size_t)64*2);
  __hip_bfloat16* uw_c   = (__hip_bfloat16*)alloc((size_t)49152*2);
  __hip_bfloat16* ub_c   = (__hip_bfloat16*)alloc((size_t)768*2);
  __hip_bfloat16* Wc     = (__hip_bfloat16*)alloc((size_t)QKV_N*EDIM*2);
  __hip_bfloat16* qkv    = (__hip_bfloat16*)alloc((size_t)M_TOT*QKV_N*2);
  __hip_bfloat16* xop    = (__hip_bfloat16*)alloc((size_t)M_TOT*EDIM*2);
  float* pO = (float*)alloc((size_t)96*NSPL*16*64*4);
  float* pm = (float*)alloc((size_t)96*NSPL*16*4);
  float* pl = (float*)alloc((size_t)96*NSPL*16*4);

  hipMemsetAsync(mznz, 0, 4, stream);

  CvBatch cb;
  const int srcIdx[7] = {3, 4, 5, 8, 9, 10, 11};
  void* dsts[7] = {bIn_c, wOut_c, bOut_c, dw_c, db_c, uw_c, ub_c};
  const int ns[7] = {2304, 589824, 768, 49152, 64, 49152, 768};
  int cum = 0;
  for (int k = 0; k < 7; ++k) {
    cb.src[k] = d_in[srcIdx[k]];
    cb.dst[k] = dsts[k];
    cb.off8[k] = cum;
    cum += ns[k] / 8;
  }
  cb.off8[7] = cum;

  prep<<<2048, 256, 0, stream>>>(d_in[0], d_in[1], x_c, mask_c, cb, flag, mznz);
  build_wc<<<2304, 256, 0, stream>>>(d_in[2], d_in[6], d_in[7], Wc, flag);

  gemm_bt_8ph<<<99*9, 512, 0, stream>>>(x_c, x_raw, Wc, bIn_c, qkv,
                                        M_TOT, QKV_N, EDIM, 9, flag, 0);
  attn_fused<<<dim3(6144), 256, 0, stream>>>(qkv, mask_c, mask_raw, flag, mznz, xop);
  cls_split<<<dim3(96*NSPL), 256, 0, stream>>>(qkv, mask_c, mask_raw, flag, mznz,
                                               top_idx, pO, pm, pl);
  gemm_bt_8ph<<<99*3, 512, 0, stream>>>(xop, xop, wOut_c, bOut_c, d_out,
                                        M_TOT, EDIM, EDIM, 3, flag, 1);
  final_cls<<<128, 256, 0, stream>>>(d_out, pO, pm, pl, wOut_c, bOut_c,
                                     dw_c, db_c, uw_c, ub_c, top_idx, flag);
}

// Round 15
// 474.799 us; speedup vs baseline: 1.1096x; 1.1096x over previous
//
#include <hip/hip_runtime.h>
#include <hip/hip_bf16.h>

typedef __attribute__((ext_vector_type(4))) float f32x4;
typedef __attribute__((ext_vector_type(8))) short s16x8;

#define BSZ 128
#define TGT 197
#define EDIM 768
#define NH 12
#define HD 64
#define NF 16
#define M_TOT (BSZ*TGT)      // 25216
#define QKV_N (3*EDIM)       // 2304
#define KG (NF*TGT)          // 3152
#define KGP 3328
#define VSTR 264
#define NSPL 8
#define KSPL 394
#define LSTR 424

__device__ __forceinline__ float b2f(unsigned short u) {
  return __uint_as_float(((unsigned int)u) << 16);
}
__device__ __forceinline__ float bf2f(__hip_bfloat16 b) { return __bfloat162float(b); }
__device__ __forceinline__ __hip_bfloat16 f2bf(float f) { return __float2bfloat16(f); }
__device__ __forceinline__ unsigned int packbf(float a, float b) {
  __hip_bfloat16 x = __float2bfloat16(a), y = __float2bfloat16(b);
  return (unsigned int)*(unsigned short*)&x | ((unsigned int)*(unsigned short*)&y << 16);
}
__device__ __forceinline__ int swz(int t, int c) {
  return t*64 + (c ^ ((((t & 7) ^ ((t >> 3) & 3))) << 3));
}
__device__ __forceinline__ int vswz(int d, int t) {
  return d*VSTR + (t ^ (d & 56));
}

__device__ __forceinline__ void gload_lds16(const void* gsrc, void* ldst) {
  __builtin_amdgcn_global_load_lds(
      (const __attribute__((address_space(1))) unsigned int*)gsrc,
      (__attribute__((address_space(3))) unsigned int*)ldst, 16, 0, 0);
}

// ---------------- dtype detection (+ init mask-zero flag to 1) ----------------
__global__ void detect_dtype(const unsigned short* __restrict__ xraw,
                             int* __restrict__ flag, int* __restrict__ mz) {
  if (threadIdx.x == 0 && blockIdx.x == 0) {
    float mx = 0.f;
    for (int j = 0; j < 1024; ++j) {
      float v = fabsf(b2f(xraw[j]));
      if (v < 1e30f) mx = fmaxf(mx, v);
      else mx = 1e30f;
    }
    *flag = (mx < 100.0f) ? 1 : 0;
    *mz = 1;
  }
}

// ---------------- mask-zero detection ----------------
__global__ __launch_bounds__(256) void detect_mask_zero(
    const unsigned int* __restrict__ mraw, int nelem,
    const int* __restrict__ flag, int* __restrict__ mz)
{
  const int isbf = *flag;
  const int nwords = isbf ? (nelem >> 1) : nelem;
  const unsigned int am = isbf ? 0x7fff7fffu : 0x7fffffffu;
  unsigned int acc = 0;
  for (int i = blockIdx.x*256 + threadIdx.x; i < nwords; i += gridDim.x*256)
    acc |= (mraw[i] & am);
  if (acc) atomicAnd(mz, 0);
}

// ---------------- canonicalize big float tensor to bf16 (skippable) ----------------
__global__ __launch_bounds__(256) void convert_bf16(
    const void* __restrict__ src, __hip_bfloat16* __restrict__ dst,
    int n8, const int* __restrict__ flag, int skip_if_bf)
{
  const int isbf = *flag;
  if (skip_if_bf && isbf) return;
  int i = blockIdx.x * 256 + threadIdx.x;
  const int stride = gridDim.x * 256;
  if (isbf) {
    const s16x8* s = (const s16x8*)src;
    s16x8* d = (s16x8*)dst;
    for (; i < n8; i += stride) d[i] = s[i];
  } else {
    const f32x4* s = (const f32x4*)src;
    s16x8* d = (s16x8*)dst;
    for (; i < n8; i += stride) {
      f32x4 a = s[i*2], b = s[i*2+1];
      s16x8 o;
      #pragma unroll
      for (int j = 0; j < 4; ++j) { __hip_bfloat16 t = f2bf(a[j]); o[j] = *(short*)&t; }
      #pragma unroll
      for (int j = 0; j < 4; ++j) { __hip_bfloat16 t = f2bf(b[j]); o[4+j] = *(short*)&t; }
      d[i] = o;
    }
  }
}

// ---------------- batched convert for the 10 small weight tensors ----------------
struct CvBatch {
  const void* src[10];
  void* dst[10];
  int off8[11];
};

__global__ __launch_bounds__(256) void convert_batch(CvBatch cb, const int* __restrict__ flag)
{
  const int isbf = *flag;
  const int total = cb.off8[10];
  for (int i = blockIdx.x*256 + threadIdx.x; i < total; i += gridDim.x*256) {
    int s = 0;
    #pragma unroll
    for (int k = 1; k < 10; ++k) s += (i >= cb.off8[k]);
    const int li = i - cb.off8[s];
    if (isbf) {
      ((s16x8*)cb.dst[s])[li] = ((const s16x8*)cb.src[s])[li];
    } else {
      const f32x4* sp = (const f32x4*)cb.src[s];
      f32x4 a = sp[li*2], b = sp[li*2+1];
      s16x8 o;
      #pragma unroll
      for (int j = 0; j < 4; ++j) { __hip_bfloat16 t = f2bf(a[j]); o[j] = *(short*)&t; }
      #pragma unroll
      for (int j = 0; j < 4; ++j) { __hip_bfloat16 t = f2bf(b[j]); o[4+j] = *(short*)&t; }
      ((s16x8*)cb.dst[s])[li] = o;
    }
  }
}

// ---------------- Wc = in_proj_weight + lora_b @ lora_a ----------------
__global__ __launch_bounds__(256) void build_wc(
    const __hip_bfloat16* __restrict__ W,
    const __hip_bfloat16* __restrict__ la,
    const __hip_bfloat16* __restrict__ lb,
    __hip_bfloat16* __restrict__ Wc)
{
  __shared__ float lbr[64];
  const int n = blockIdx.x;
  if (threadIdx.x < 64) lbr[threadIdx.x] = bf2f(lb[n*64 + threadIdx.x]);
  __syncthreads();
  for (int e = threadIdx.x; e < EDIM; e += 256) {
    float acc = bf2f(W[(size_t)n*EDIM + e]);
    for (int r = 0; r < 64; ++r) acc += lbr[r] * bf2f(la[r*EDIM + e]);
    Wc[(size_t)n*EDIM + e] = f2bf(acc);
  }
}

// ---------------- 256x256 8-phase GEMM (round-8 spread-prefetch schedule) ----------------
__global__ __launch_bounds__(512) void gemm_bt_8ph(
    const __hip_bfloat16* __restrict__ A,
    const __hip_bfloat16* __restrict__ A_alt,
    const __hip_bfloat16* __restrict__ B,
    const __hip_bfloat16* __restrict__ bias,
    void* __restrict__ C,
    int M, int N, int K, int ntiles,
    const int* __restrict__ flag, int flag_mode)
{
  __shared__ char lds[131072];
  const int tid = threadIdx.x;
  const int wave = tid >> 6, lane = tid & 63;
  const int l16 = lane & 15, kq = lane >> 4;
  const int wr = wave >> 2, wc2 = wave & 3;

  const int nwg = gridDim.x;
  const int bid = blockIdx.x;
  const int qc = nwg >> 3, rc = nwg & 7;
  const int xcd = bid & 7;
  const int wgid = (xcd < rc ? xcd*(qc+1) : rc*(qc+1) + (xcd-rc)*qc) + (bid >> 3);
  const long brow = (long)(wgid / ntiles) * 256;
  const long bcol = (long)(wgid % ntiles) * 256;

  const int isbf = *flag;
  const __hip_bfloat16* Ause = isbf ? A_alt : A;
  const int nkt = K >> 6;

  const int srow = tid >> 3;
  const int schunk = tid & 7;
  const int wuni = wave << 10;

  auto stA = [&](int t, int buf, int issue) {
    int ar = issue*64 + srow;
    int cs = schunk ^ (ar & 7);
    long gr = brow + ar; if (gr > (long)M - 1) gr = M - 1;
    gload_lds16(Ause + gr*(long)K + t*64 + cs*8,
                lds + buf*65536 + issue*8192 + wuni);
  };
  auto stB = [&](int t, int buf, int issue) {
    int br = issue*64 + srow;
    int cs = schunk ^ (br & 7);
    gload_lds16(B + (bcol + br)*(long)K + t*64 + cs*8,
                lds + buf*65536 + 32768 + issue*8192 + wuni);
  };
  auto rdA = [&](int buf, int q, int a, int ks) -> s16x8 {
    int ar = wr*128 + q*32 + a*16 + l16;
    int ch = ks*4 + kq;
    return *(const s16x8*)(lds + buf*65536 + ar*128 + ((ch ^ (ar & 7)) << 4));
  };
  auto rdB = [&](int buf, int ni, int ks) -> s16x8 {
    int br = wc2*64 + ni*16 + l16;
    int ch = ks*4 + kq;
    return *(const s16x8*)(lds + buf*65536 + 32768 + br*128 + ((ch ^ (br & 7)) << 4));
  };

  f32x4 acc[8][4];
  #pragma unroll
  for (int i = 0; i < 8; ++i)
    #pragma unroll
    for (int j = 0; j < 4; ++j) acc[i][j] = (f32x4){0.f,0.f,0.f,0.f};

  stB(0,0,0); stB(0,0,1); stB(0,0,2); stB(0,0,3);
  stA(0,0,0); stA(0,0,2); stA(0,0,1); stA(0,0,3);
  asm volatile("s_waitcnt vmcnt(2)" ::: "memory");
  __builtin_amdgcn_s_barrier();

  for (int t = 0; t < nkt; ++t) {
    const int cur = t & 1, nxt = cur ^ 1;
    const bool pf = (t + 1 < nkt);
    s16x8 bfr[4][2], af[2][2];

    #pragma unroll
    for (int ni = 0; ni < 4; ++ni) { bfr[ni][0] = rdB(cur,ni,0); bfr[ni][1] = rdB(cur,ni,1); }
    af[0][0]=rdA(cur,0,0,0); af[0][1]=rdA(cur,0,0,1);
    af[1][0]=rdA(cur,0,1,0); af[1][1]=rdA(cur,0,1,1);
    if (pf) { stB(t+1,nxt,0); stB(t+1,nxt,1); }
    __builtin_amdgcn_s_barrier();
    asm volatile("s_waitcnt lgkmcnt(0)" ::: "memory");
    __builtin_amdgcn_sched_barrier(0);
    __builtin_amdgcn_s_setprio(1);
    #pragma unroll
    for (int ks = 0; ks < 2; ++ks)
      #pragma unroll
      for (int ni = 0; ni < 4; ++ni) {
        acc[0][ni] = __builtin_amdgcn_mfma_f32_16x16x32_bf16(af[0][ks], bfr[ni][ks], acc[0][ni], 0,0,0);
        acc[1][ni] = __builtin_amdgcn_mfma_f32_16x16x32_bf16(af[1][ks], bfr[ni][ks], acc[1][ni], 0,0,0);
      }
    __builtin_amdgcn_s_setprio(0);

    af[0][0]=rdA(cur,1,0,0); af[0][1]=rdA(cur,1,0,1);
    af[1][0]=rdA(cur,1,1,0); af[1][1]=rdA(cur,1,1,1);
    if (pf) {
      stB(t+1,nxt,2); stB(t+1,nxt,3);
      asm volatile("s_waitcnt vmcnt(4)" ::: "memory");
    } else {
      asm volatile("s_waitcnt vmcnt(0)" ::: "memory");
    }
    __builtin_amdgcn_s_barrier();
    asm volatile("s_waitcnt lgkmcnt(0)" ::: "memory");
    __builtin_amdgcn_sched_barrier(0);
    __builtin_amdgcn_s_setprio(1);
    #pragma unroll
    for (int ks = 0; ks < 2; ++ks)
      #pragma unroll
      for (int ni = 0; ni < 4; ++ni) {
        acc[2][ni] = __builtin_amdgcn_mfma_f32_16x16x32_bf16(af[0][ks], bfr[ni][ks], acc[2][ni], 0,0,0);
        acc[3][ni] = __builtin_amdgcn_mfma_f32_16x16x32_bf16(af[1][ks], bfr[ni][ks], acc[3][ni], 0,0,0);
      }
    __builtin_amdgcn_s_setprio(0);

    af[0][0]=rdA(cur,2,0,0); af[0][1]=rdA(cur,2,0,1);
    af[1][0]=rdA(cur,2,1,0); af[1][1]=rdA(cur,2,1,1);
    if (pf) { stA(t+1,nxt,0); stA(t+1,nxt,2); }
    __builtin_amdgcn_s_barrier();
    asm volatile("s_waitcnt lgkmcnt(0)" ::: "memory");
    __builtin_amdgcn_sched_barrier(0);
    __builtin_amdgcn_s_setprio(1);
    #pragma unroll
    for (int ks = 0; ks < 2; ++ks)
      #pragma unroll
      for (int ni = 0; ni < 4; ++ni) {
        acc[4][ni] = __builtin_amdgcn_mfma_f32_16x16x32_bf16(af[0][ks], bfr[ni][ks], acc[4][ni], 0,0,0);
        acc[5][ni] = __builtin_amdgcn_mfma_f32_16x16x32_bf16(af[1][ks], bfr[ni][ks], acc[5][ni], 0,0,0);
      }
    __builtin_amdgcn_s_setprio(0);

    af[0][0]=rdA(cur,3,0,0); af[0][1]=rdA(cur,3,0,1);
    af[1][0]=rdA(cur,3,1,0); af[1][1]=rdA(cur,3,1,1);
    if (pf) { stA(t+1,nxt,1); stA(t+1,nxt,3); }
    asm volatile("s_waitcnt vmcnt(2)" ::: "memory");
    __builtin_amdgcn_s_barrier();
    asm volatile("s_waitcnt lgkmcnt(0)" ::: "memory");
    __builtin_amdgcn_sched_barrier(0);
    __builtin_amdgcn_s_setprio(1);
    #pragma unroll
    for (int ks = 0; ks < 2; ++ks)
      #pragma unroll
      for (int ni = 0; ni < 4; ++ni) {
        acc[6][ni] = __builtin_amdgcn_mfma_f32_16x16x32_bf16(af[0][ks], bfr[ni][ks], acc[6][ni], 0,0,0);
        acc[7][ni] = __builtin_amdgcn_mfma_f32_16x16x32_bf16(af[1][ks], bfr[ni][ks], acc[7][ni], 0,0,0);
      }
    __builtin_amdgcn_s_setprio(0);
  }

  __builtin_amdgcn_s_barrier();

  const int f32o = flag_mode && (!isbf);
  float bv[4];
  #pragma unroll
  for (int ni = 0; ni < 4; ++ni) bv[ni] = bf2f(bias[bcol + wc2*64 + ni*16 + l16]);
  const int o4 = kq*4;

  if (!f32o) {
    __hip_bfloat16* eb = (__hip_bfloat16*)(lds + wave*2048);
    __hip_bfloat16* Cb = (__hip_bfloat16*)C;
    const int rr = lane >> 3, cg = lane & 7;
    #pragma unroll
    for (int mi = 0; mi < 8; ++mi) {
      #pragma unroll
      for (int ni = 0; ni < 4; ++ni)
        #pragma unroll
        for (int r = 0; r < 4; ++r) {
          const int row16 = o4 + r;
          const int sidx = row16*64 + ((((ni*2 + (l16 >> 3)) ^ (row16 & 7)) << 3) | (l16 & 7));
          eb[sidx] = f2bf(acc[mi][ni][r] + bv[ni]);
        }
      asm volatile("s_waitcnt lgkmcnt(0)" ::: "memory");
      __builtin_amdgcn_sched_barrier(0);
      #pragma unroll
      for (int pass = 0; pass < 2; ++pass) {
        const int row16 = pass*8 + rr;
        const long grow = brow + wr*128 + mi*16 + row16;
        if (grow < M) {
          s16x8 v = *(const s16x8*)(eb + row16*64 + ((cg ^ (row16 & 7)) << 3));
          *(s16x8*)(Cb + grow*(long)N + bcol + wc2*64 + cg*8) = v;
        }
      }
      asm volatile("s_waitcnt lgkmcnt(0)" ::: "memory");
      __builtin_amdgcn_sched_barrier(0);
    }
  } else {
    #pragma unroll
    for (int mi = 0; mi < 8; ++mi)
      #pragma unroll
      for (int ni = 0; ni < 4; ++ni)
        #pragma unroll
        for (int r = 0; r < 4; ++r) {
          const long grow = brow + wr*128 + mi*16 + o4 + r;
          if (grow < M)
            ((float*)C)[grow*(long)N + bcol + wc2*64 + ni*16 + l16] = acc[mi][ni][r] + bv[ni];
        }
  }
}

// ---------------- fused attention: V^T-only LDS, K direct from global ----------------
__global__ __launch_bounds__(256) void attn_fused(
    const __hip_bfloat16* __restrict__ qkv,
    const __hip_bfloat16* __restrict__ mask,
    const __hip_bfloat16* __restrict__ mask_raw,
    const int* __restrict__ flag,
    const int* __restrict__ mzp,
    __hip_bfloat16* __restrict__ xop)
{
  __shared__ __hip_bfloat16 lVt[64*VSTR];

  const int tid = threadIdx.x;
  const int blk = blockIdx.x;
  const int xcd = blk & 7;
  const int slot = blk >> 3;
  const int ih = xcd * 192 + (slot >> 2);
  const int qt = slot & 3;
  const int h = ih % NH;
  const int i = ih / NH;
  const int q0 = qt * 64;
  const size_t rowbase = (size_t)i * TGT;
  const int wave = tid >> 6, lane = tid & 63;
  const int l16 = lane & 15, kq = lane >> 4;
  const int mz = *mzp;
  const __hip_bfloat16* msk = (*flag) ? mask_raw : mask;

  int qr = q0 + wave*16 + l16;
  const int qrc = qr > TGT-1 ? TGT-1 : qr;
  s16x8 qf[2];
  #pragma unroll
  for (int kk = 0; kk < 2; ++kk)
    qf[kk] = *(const s16x8*)(qkv + (rowbase + qrc)*QKV_N + h*HD + kk*32 + kq*8);

  const f32x4 z = {0.f,0.f,0.f,0.f};
  for (int idx = tid; idx < 224*8; idx += 256) {
    int t = idx >> 3, c8 = idx & 7;
    f32x4 vv = z;
    if (t < TGT) vv = *(const f32x4*)(qkv + (rowbase + t)*QKV_N + 2*EDIM + h*HD + c8*8);
    const __hip_bfloat16* pv = (const __hip_bfloat16*)&vv;
    const int tx = t ^ (c8 << 3);
    #pragma unroll
    for (int j = 0; j < 8; ++j)
      lVt[(c8*8 + j)*VSTR + tx] = pv[j];
  }
  __syncthreads();

  f32x4 acc[14];
  #pragma unroll
  for (int nf = 0; nf < 14; ++nf) {
    int trow = nf*16 + l16; if (trow > TGT-1) trow = TGT-1;
    acc[nf] = (f32x4){0.f,0.f,0.f,0.f};
    #pragma unroll
    for (int kk = 0; kk < 2; ++kk) {
      s16x8 kf = *(const s16x8*)(qkv + (rowbase + trow)*QKV_N + EDIM + h*HD + kk*32 + kq*8);
      acc[nf] = __builtin_amdgcn_mfma_f32_16x16x32_bf16(kf, qf[kk], acc[nf], 0, 0, 0);
    }
  }

  float mx = -1e30f;
  #pragma unroll
  for (int nf = 0; nf < 14; ++nf) {
    #pragma unroll
    for (int r = 0; r < 4; ++r) {
      const int t = nf*16 + kq*4 + r;
      float s;
      if (t < TGT) {
        s = acc[nf][r]*0.125f;
        if (!mz) s += bf2f(msk[(rowbase + qrc)*TGT + t]);
      } else s = -1e30f;
      acc[nf][r] = s;
      mx = fmaxf(mx, s);
    }
  }
  mx = fmaxf(mx, __shfl_xor(mx, 16));
  mx = fmaxf(mx, __shfl_xor(mx, 32));

  float rs = 0.f;
  unsigned int pk[14][2];
  #pragma unroll
  for (int nf = 0; nf < 14; ++nf) {
    float p0 = __expf(acc[nf][0] - mx);
    float p1 = __expf(acc[nf][1] - mx);
    float p2 = __expf(acc[nf][2] - mx);
    float p3 = __expf(acc[nf][3] - mx);
    rs += (p0 + p1) + (p2 + p3);
    pk[nf][0] = packbf(p0, p1);
    pk[nf][1] = packbf(p2, p3);
  }
  rs += __shfl_xor(rs, 16);
  rs += __shfl_xor(rs, 32);

  f32x4 oacc[4];
  #pragma unroll
  for (int nf = 0; nf < 4; ++nf) oacc[nf] = (f32x4){0.f,0.f,0.f,0.f};

  const int slbase = l16 + ((kq & 1) << 5);
  #pragma unroll
  for (int kt = 0; kt < 7; ++kt) {
    s16x8 pa;
    #pragma unroll
    for (int jp = 0; jp < 4; ++jp) {
      const int srcLane = slbase + ((jp >> 1) << 4);
      int va = __shfl((int)pk[2*kt][jp & 1], srcLane, 64);
      int vb = __shfl((int)pk[2*kt + 1][jp & 1], srcLane, 64);
      int sel = (kq < 2) ? va : vb;
      pa[2*jp]     = (short)(sel & 0xffff);
      pa[2*jp + 1] = (short)(((unsigned int)sel) >> 16);
    }
    #pragma unroll
    for (int nf = 0; nf < 4; ++nf) {
      s16x8 vf = *(const s16x8*)(lVt + vswz(nf*16 + l16, kt*32 + kq*8));
      oacc[nf] = __builtin_amdgcn_mfma_f32_16x16x32_bf16(pa, vf, oacc[nf], 0, 0, 0);
    }
  }

  #pragma unroll
  for (int r = 0; r < 4; ++r) {
    const float rsrc = __shfl(rs, kq*4 + r, 64);
    const int qw = q0 + wave*16 + kq*4 + r;
    if (qw < TGT) {
      const float inv = 1.0f / rsrc;
      #pragma unroll
      for (int nf = 0; nf < 4; ++nf)
        xop[(rowbase + qw)*(size_t)EDIM + h*HD + nf*16 + l16] = f2bf(oacc[nf][r] * inv);
    }
  }
}

// ---------------- CLS split-K attention: block = (gh, split of 394 keys) ----------
__global__ __launch_bounds__(256) void cls_split(
    const __hip_bfloat16* __restrict__ qkv,
    const __hip_bfloat16* __restrict__ mask,
    const __hip_bfloat16* __restrict__ mask_raw,
    const int* __restrict__ flag,
    const int* __restrict__ mzp,
    const int* __restrict__ top_idx,
    float* __restrict__ pO,    // [96*8][16][64]
    float* __restrict__ pm,    // [96*8][16]
    float* __restrict__ pl)    // [96*8][16]
{
  __shared__ __hip_bfloat16 lQ[16*64];
  __shared__ __hip_bfloat16 lS[16*LSTR];
  __shared__ __hip_bfloat16 lV[256*64];
  __shared__ float red[16][17];
  __shared__ float rmax[16];
  __shared__ float rsum[16];

  const int tid = threadIdx.x;
  const int sp = blockIdx.x & 7;
  const int gh = blockIdx.x >> 3;
  const int g = gh / NH;
  const int h = gh % NH;
  const int k0 = sp * KSPL;
  const int wave = tid >> 6, lane = tid & 63;
  const int l16 = lane & 15, kq = lane >> 4, o4 = (lane >> 4) * 4;
  const int mz = *mzp;
  const __hip_bfloat16* msk = (*flag) ? mask_raw : mask;

  if (tid < 128) {
    int qi = tid >> 3, c8 = tid & 7;
    int ib = g*NF + qi;
    int top = top_idx[ib];
    f32x4 v = *(const f32x4*)(qkv + ((size_t)ib*TGT + top)*QKV_N + h*HD + c8*8);
    *(f32x4*)(lQ + qi*64 + c8*8) = v;
  }
  __syncthreads();

  s16x8 q8[2];
  #pragma unroll
  for (int kk = 0; kk < 2; ++kk)
    q8[kk] = *(const s16x8*)(lQ + l16*64 + kk*32 + kq*8);

  for (int nf = wave; nf < 26; nf += 4) {
    const int keyl = nf*16 + l16;
    const int keyg = k0 + (keyl < KSPL ? keyl : 0);
    f32x4 a = {0.f,0.f,0.f,0.f};
    const size_t krow = (size_t)g*KG + keyg;
    #pragma unroll
    for (int kk = 0; kk < 2; ++kk) {
      s16x8 k8 = *(const s16x8*)(qkv + krow*QKV_N + EDIM + h*HD + kk*32 + kq*8);
      a = __builtin_amdgcn_mfma_f32_16x16x32_bf16(q8[kk], k8, a, 0, 0, 0);
    }
    float mval = 0.f;
    if (!mz && keyl < KSPL) {
      const int f = keyg / 197;
      const int t = keyg - f*197;
      mval = bf2f(msk[((size_t)(g*NF + f)*TGT + (TGT-1))*TGT + t]);
    }
    #pragma unroll
    for (int r = 0; r < 4; ++r)
      lS[(o4 + r)*LSTR + nf*16 + l16] = f2bf(keyl < KSPL ? a[r]*0.125f + mval : -1e30f);
  }
  __syncthreads();

  {
    const int q = tid >> 4, c = tid & 15;
    float mx = -1e30f;
    for (int gch = c; gch < 52; gch += 16) {
      s16x8 sv = *(const s16x8*)(lS + q*LSTR + gch*8);
      #pragma unroll
      for (int j = 0; j < 8; ++j) mx = fmaxf(mx, b2f((unsigned short)sv[j]));
    }
    red[q][c] = mx;
    __syncthreads();
    if (tid < 16) {
      float m = red[tid][0];
      for (int j = 1; j < 16; ++j) m = fmaxf(m, red[tid][j]);
      rmax[tid] = m;
    }
    __syncthreads();
    const float rowmax = rmax[q];
    float sum = 0.f;
    for (int gch = c; gch < 52; gch += 16) {
      s16x8 sv = *(const s16x8*)(lS + q*LSTR + gch*8);
      s16x8 ov;
      #pragma unroll
      for (int jp = 0; jp < 4; ++jp) {
        float e0 = __expf(b2f((unsigned short)sv[2*jp])   - rowmax);
        float e1 = __expf(b2f((unsigned short)sv[2*jp+1]) - rowmax);
        sum += e0 + e1;
        unsigned int pr = packbf(e0, e1);
        ov[2*jp]   = (short)(pr & 0xffff);
        ov[2*jp+1] = (short)(pr >> 16);
      }
      *(s16x8*)(lS + q*LSTR + gch*8) = ov;
    }
    red[q][c] = sum;
    __syncthreads();
    if (tid < 16) {
      float s = 0.f;
      for (int j = 0; j < 16; ++j) s += red[tid][j];
      rsum[tid] = s;
    }
  }

  f32x4 oa = {0.f,0.f,0.f,0.f};
  const f32x4 z = {0.f,0.f,0.f,0.f};
  #pragma unroll
  for (int cki = 0; cki < 2; ++cki) {
    const int ck = cki * 256;
    const int nrows = cki ? 160 : 256;
    const int nks = cki ? 5 : 8;
    __syncthreads();
    for (int idx = tid; idx < nrows*8; idx += 256) {
      int t2 = idx >> 3, c8 = idx & 7;
      int keyl = ck + t2;
      f32x4 v = z;
      if (keyl < KSPL)
        v = *(const f32x4*)(qkv + ((size_t)g*KG + k0 + keyl)*QKV_N + 2*EDIM + h*HD + c8*8);
      *(f32x4*)(lV + swz(t2, c8*8)) = v;
    }
    __syncthreads();
    for (int ks = 0; ks < nks; ++ks) {
      s16x8 pa = *(const s16x8*)(lS + l16*LSTR + ck + ks*32 + kq*8);
      s16x8 vf;
      #pragma unroll
      for (int j = 0; j < 8; ++j) {
        const int t2 = ks*32 + kq*8 + j;
        vf[j] = *(const short*)(lV + swz(t2, wave*16 + l16));
      }
      oa = __builtin_amdgcn_mfma_f32_16x16x32_bf16(pa, vf, oa, 0, 0, 0);
    }
  }

  const int ps = gh*NSPL + sp;
  #pragma unroll
  for (int r = 0; r < 4; ++r)
    pO[((size_t)ps*16 + (o4 + r))*64 + wave*16 + l16] = oa[r];
  if (tid < 16) {
    pm[ps*16 + tid] = rmax[tid];
    pl[ps*16 + tid] = rsum[tid];
  }
}

// ---------------- CLS combine: rescale partials, write x1b ----------------
__global__ __launch_bounds__(256) void cls_combine(
    const float* __restrict__ pO,
    const float* __restrict__ pm,
    const float* __restrict__ pl,
    __hip_bfloat16* __restrict__ x1buf)
{
  __shared__ float M[16];
  __shared__ float L[16];
  __shared__ float sc[NSPL][16];
  const int tid = threadIdx.x;
  const int gh = blockIdx.x;
  const int g = gh / NH;
  const int h = gh % NH;

  if (tid < 16) {
    float m = -1e30f;
    for (int s = 0; s < NSPL; ++s) m = fmaxf(m, pm[(gh*NSPL + s)*16 + tid]);
    M[tid] = m;
  }
  __syncthreads();
  if (tid < 128) {
    const int s = tid >> 4, q = tid & 15;
    sc[s][q] = __expf(pm[(gh*NSPL + s)*16 + q] - M[q]);
  }
  __syncthreads();
  if (tid < 16) {
    float l = 0.f;
    for (int s = 0; s < NSPL; ++s) l += pl[(gh*NSPL + s)*16 + tid] * sc[s][tid];
    L[tid] = l;
  }
  __syncthreads();
  for (int idx = tid; idx < 16*64; idx += 256) {
    const int q = idx >> 6, d = idx & 63;
    float acc = 0.f;
    for (int s = 0; s < NSPL; ++s)
      acc += pO[((size_t)(gh*NSPL + s)*16 + q)*64 + d] * sc[s][q];
    x1buf[((size_t)(g*NF + q))*EDIM + h*64 + d] = f2bf(acc / L[q]);
  }
}

// ---------------- LoRA head + CLS row update ----------------
__global__ __launch_bounds__(256) void final_update(
    void* __restrict__ out,
    const __hip_bfloat16* __restrict__ x1p,
    const __hip_bfloat16* __restrict__ dw, const __hip_bfloat16* __restrict__ db,
    const __hip_bfloat16* __restrict__ uw, const __hip_bfloat16* __restrict__ ub,
    const int* __restrict__ top_idx, const int* __restrict__ flag)
{
  __shared__ float x0[EDIM];
  __shared__ float hmid[64];
  const int i = blockIdx.x;
  const int tid = threadIdx.x;
  const int top = top_idx[i];
  const int isbf = *flag;
  const size_t rowoff = ((size_t)i*TGT + top)*EDIM;
  for (int e = tid; e < EDIM; e += 256)
    x0[e] = isbf ? bf2f(((const __hip_bfloat16*)out)[rowoff + e])
                 : ((const float*)out)[rowoff + e];
  __syncthreads();
  if (tid < 64) {
    float a = bf2f(db[tid]);
    for (int e = 0; e < EDIM; ++e) a += x0[e] * bf2f(dw[tid*EDIM + e]);
    hmid[tid] = a / (1.f + __expf(-1.702f * a));
  }
  __syncthreads();
  for (int e = tid; e < EDIM; e += 256) {
    float a = bf2f(ub[e]) + bf2f(x1p[(size_t)i*EDIM + e]);
    #pragma unroll
    for (int r = 0; r < 64; ++r) a += hmid[r] * bf2f(uw[e*64 + r]);
    if (isbf) ((__hip_bfloat16*)out)[rowoff + e] = f2bf(a);
    else ((float*)out)[rowoff + e] = a;
  }
}

extern "C" void kernel_launch(void* const* d_in, const int* in_sizes, int n_in,
                              void* d_out, int out_size, void* d_ws, size_t ws_size,
                              hipStream_t stream) {
  (void)in_sizes; (void)n_in; (void)out_size; (void)ws_size;
  const int* top_idx = (const int*)d_in[13];
  const __hip_bfloat16* x_raw    = (const __hip_bfloat16*)d_in[0];
  const __hip_bfloat16* mask_raw = (const __hip_bfloat16*)d_in[1];

  char* ws = (char*)d_ws;
  size_t off = 0;
  auto alloc = [&](size_t bytes) { char* p = ws + off; off += (bytes + 15) & ~(size_t)15; return p; };

  int* flag = (int*)alloc(16);
  int* mz   = (int*)alloc(16);
  __hip_bfloat16* x_c    = (__hip_bfloat16*)alloc((size_t)19365888*2);
  __hip_bfloat16* mask_c = (__hip_bfloat16*)alloc((size_t)4967552*2);
  __hip_bfloat16* wIn_c  = (__hip_bfloat16*)alloc((size_t)1769472*2);
  __hip_bfloat16* bIn_c  = (__hip_bfloat16*)alloc((size_t)2304*2);
  __hip_bfloat16* wOut_c = (__hip_bfloat16*)alloc((size_t)589824*2);
  __hip_bfloat16* bOut_c = (__hip_bfloat16*)alloc((size_t)768*2);
  __hip_bfloat16* la_c   = (__hip_bfloat16*)alloc((size_t)49152*2);
  __hip_bfloat16* lb_c   = (__hip_bfloat16*)alloc((size_t)147456*2);
  __hip_bfloat16* dw_c   = (__hip_bfloat16*)alloc((size_t)49152*2);
  __hip_bfloat16* db_c   = (__hip_bfloat16*)alloc((size_t)64*2);
  __hip_bfloat16* uw_c   = (__hip_bfloat16*)alloc((size_t)49152*2);
  __hip_bfloat16* ub_c   = (__hip_bfloat16*)alloc((size_t)768*2);
  __hip_bfloat16* Wc     = (__hip_bfloat16*)alloc((size_t)QKV_N*EDIM*2);
  __hip_bfloat16* qkv    = (__hip_bfloat16*)alloc((size_t)M_TOT*QKV_N*2);
  __hip_bfloat16* xop    = (__hip_bfloat16*)alloc((size_t)M_TOT*EDIM*2);
  __hip_bfloat16* x1b    = (__hip_bfloat16*)alloc((size_t)BSZ*EDIM*2);
  __hip_bfloat16* x1p    = (__hip_bfloat16*)alloc((size_t)BSZ*EDIM*2);
  float* pO = (float*)alloc((size_t)96*NSPL*16*64*4);
  float* pm = (float*)alloc((size_t)96*NSPL*16*4);
  float* pl = (float*)alloc((size_t)96*NSPL*16*4);

  detect_dtype<<<1, 64, 0, stream>>>((const unsigned short*)d_in[0], flag, mz);
  detect_mask_zero<<<2048, 256, 0, stream>>>((const unsigned int*)d_in[1], 4967552, flag, mz);

  convert_bf16<<<2048, 256, 0, stream>>>(d_in[0], x_c, 19365888/8, flag, 1);
  convert_bf16<<<2048, 256, 0, stream>>>(d_in[1], mask_c, 4967552/8, flag, 1);

  CvBatch cb;
  const int srcIdx[10] = {2,3,4,5,6,7,8,9,10,11};
  void* dsts[10] = {wIn_c, bIn_c, wOut_c, bOut_c, la_c, lb_c, dw_c, db_c, uw_c, ub_c};
  const int ns[10] = {1769472, 2304, 589824, 768, 49152, 147456, 49152, 64, 49152, 768};
  int cum = 0;
  for (int k = 0; k < 10; ++k) {
    cb.src[k] = d_in[srcIdx[k]];
    cb.dst[k] = dsts[k];
    cb.off8[k] = cum;
    cum += ns[k] / 8;
  }
  cb.off8[10] = cum;
  convert_batch<<<(cum + 255)/256, 256, 0, stream>>>(cb, flag);

  build_wc<<<2304, 256, 0, stream>>>(wIn_c, la_c, lb_c, Wc);

  gemm_bt_8ph<<<99*9, 512, 0, stream>>>(x_c, x_raw, Wc, bIn_c, qkv,
                                        M_TOT, QKV_N, EDIM, 9, flag, 0);
  attn_fused<<<dim3(6144), 256, 0, stream>>>(qkv, mask_c, mask_raw, flag, mz, xop);
  cls_split<<<dim3(96*NSPL), 256, 0, stream>>>(qkv, mask_c, mask_raw, flag, mz,
                                               top_idx, pO, pm, pl);
  gemm_bt_8ph<<<99*3, 512, 0, stream>>>(xop, xop, wOut_c, bOut_c, d_out,
                                        M_TOT, EDIM, EDIM, 3, flag, 1);
  cls_combine<<<dim3(96), 256, 0, stream>>>(pO, pm, pl, x1b);
  gemm_bt_8ph<<<3, 512, 0, stream>>>(x1b, x1b, wOut_c, bOut_c, x1p,
                                     BSZ, EDIM, EDIM, 3, flag, 0);
  final_update<<<128, 256, 0, stream>>>(d_out, x1p, dw_c, db_c, uw_c, ub_c, top_idx, flag);
}

// Round 16
// 462.739 us; speedup vs baseline: 1.1385x; 1.0261x over previous
//
#include <hip/hip_runtime.h>
#include <hip/hip_bf16.h>

typedef __attribute__((ext_vector_type(4))) float f32x4;
typedef __attribute__((ext_vector_type(8))) short s16x8;

#define BSZ 128
#define TGT 197
#define EDIM 768
#define NH 12
#define HD 64
#define NF 16
#define M_TOT (BSZ*TGT)      // 25216
#define QKV_N (3*EDIM)       // 2304
#define KG (NF*TGT)          // 3152
#define VSTR 264
#define NSPL 8
#define KSPL 394
#define LSTR 424
#define NGEMM_OP 297         // out-proj gemm blocks (99 m-tiles x 3 n-tiles)

__device__ __forceinline__ float b2f(unsigned short u) {
  return __uint_as_float(((unsigned int)u) << 16);
}
__device__ __forceinline__ float bf2f(__hip_bfloat16 b) { return __bfloat162float(b); }
__device__ __forceinline__ __hip_bfloat16 f2bf(float f) { return __float2bfloat16(f); }
__device__ __forceinline__ unsigned int packbf(float a, float b) {
  __hip_bfloat16 x = __float2bfloat16(a), y = __float2bfloat16(b);
  return (unsigned int)*(unsigned short*)&x | ((unsigned int)*(unsigned short*)&y << 16);
}
__device__ __forceinline__ int swz(int t, int c) {
  return t*64 + (c ^ ((((t & 7) ^ ((t >> 3) & 3))) << 3));
}
__device__ __forceinline__ int vswz(int d, int t) {
  return d*VSTR + (t ^ (d & 56));
}

__device__ __forceinline__ void gload_lds16(const void* gsrc, void* ldst) {
  __builtin_amdgcn_global_load_lds(
      (const __attribute__((address_space(1))) unsigned int*)gsrc,
      (__attribute__((address_space(3))) unsigned int*)ldst, 16, 0, 0);
}

// ---------------- dtype detection (+ init mask-zero flag to 1) ----------------
__global__ void detect_dtype(const unsigned short* __restrict__ xraw,
                             int* __restrict__ flag, int* __restrict__ mz) {
  if (threadIdx.x == 0 && blockIdx.x == 0) {
    float mx = 0.f;
    for (int j = 0; j < 1024; ++j) {
      float v = fabsf(b2f(xraw[j]));
      if (v < 1e30f) mx = fmaxf(mx, v);
      else mx = 1e30f;
    }
    *flag = (mx < 100.0f) ? 1 : 0;
    *mz = 1;
  }
}

// ---------------- mask-zero detection ----------------
__global__ __launch_bounds__(256) void detect_mask_zero(
    const unsigned int* __restrict__ mraw, int nelem,
    const int* __restrict__ flag, int* __restrict__ mz)
{
  const int isbf = *flag;
  const int nwords = isbf ? (nelem >> 1) : nelem;
  const unsigned int am = isbf ? 0x7fff7fffu : 0x7fffffffu;
  unsigned int acc = 0;
  for (int i = blockIdx.x*256 + threadIdx.x; i < nwords; i += gridDim.x*256)
    acc |= (mraw[i] & am);
  if (acc) atomicAnd(mz, 0);
}

// ---------------- canonicalize big float tensor to bf16 (skippable) ----------------
__global__ __launch_bounds__(256) void convert_bf16(
    const void* __restrict__ src, __hip_bfloat16* __restrict__ dst,
    int n8, const int* __restrict__ flag, int skip_if_bf)
{
  const int isbf = *flag;
  if (skip_if_bf && isbf) return;
  int i = blockIdx.x * 256 + threadIdx.x;
  const int stride = gridDim.x * 256;
  if (isbf) {
    const s16x8* s = (const s16x8*)src;
    s16x8* d = (s16x8*)dst;
    for (; i < n8; i += stride) d[i] = s[i];
  } else {
    const f32x4* s = (const f32x4*)src;
    s16x8* d = (s16x8*)dst;
    for (; i < n8; i += stride) {
      f32x4 a = s[i*2], b = s[i*2+1];
      s16x8 o;
      #pragma unroll
      for (int j = 0; j < 4; ++j) { __hip_bfloat16 t = f2bf(a[j]); o[j] = *(short*)&t; }
      #pragma unroll
      for (int j = 0; j < 4; ++j) { __hip_bfloat16 t = f2bf(b[j]); o[4+j] = *(short*)&t; }
      d[i] = o;
    }
  }
}

// ---------------- batched convert for the 10 small weight tensors ----------------
struct CvBatch {
  const void* src[10];
  void* dst[10];
  int off8[11];
};

__global__ __launch_bounds__(256) void convert_batch(CvBatch cb, const int* __restrict__ flag)
{
  const int isbf = *flag;
  const int total = cb.off8[10];
  for (int i = blockIdx.x*256 + threadIdx.x; i < total; i += gridDim.x*256) {
    int s = 0;
    #pragma unroll
    for (int k = 1; k < 10; ++k) s += (i >= cb.off8[k]);
    const int li = i - cb.off8[s];
    if (isbf) {
      ((s16x8*)cb.dst[s])[li] = ((const s16x8*)cb.src[s])[li];
    } else {
      const f32x4* sp = (const f32x4*)cb.src[s];
      f32x4 a = sp[li*2], b = sp[li*2+1];
      s16x8 o;
      #pragma unroll
      for (int j = 0; j < 4; ++j) { __hip_bfloat16 t = f2bf(a[j]); o[j] = *(short*)&t; }
      #pragma unroll
      for (int j = 0; j < 4; ++j) { __hip_bfloat16 t = f2bf(b[j]); o[4+j] = *(short*)&t; }
      ((s16x8*)cb.dst[s])[li] = o;
    }
  }
}

// ---------------- Wc = in_proj_weight + lora_b @ lora_a ----------------
__global__ __launch_bounds__(256) void build_wc(
    const __hip_bfloat16* __restrict__ W,
    const __hip_bfloat16* __restrict__ la,
    const __hip_bfloat16* __restrict__ lb,
    __hip_bfloat16* __restrict__ Wc)
{
  __shared__ float lbr[64];
  const int n = blockIdx.x;
  if (threadIdx.x < 64) lbr[threadIdx.x] = bf2f(lb[n*64 + threadIdx.x]);
  __syncthreads();
  for (int e = threadIdx.x; e < EDIM; e += 256) {
    float acc = bf2f(W[(size_t)n*EDIM + e]);
    for (int r = 0; r < 64; ++r) acc += lbr[r] * bf2f(la[r*EDIM + e]);
    Wc[(size_t)n*EDIM + e] = f2bf(acc);
  }
}

// ---------------- 256x256 8-phase GEMM (round-8 spread-prefetch schedule) ----------------
__global__ __launch_bounds__(512) void gemm_bt_8ph(
    const __hip_bfloat16* __restrict__ A,
    const __hip_bfloat16* __restrict__ A_alt,
    const __hip_bfloat16* __restrict__ B,
    const __hip_bfloat16* __restrict__ bias,
    void* __restrict__ C,
    int M, int N, int K, int ntiles,
    const int* __restrict__ flag, int flag_mode)
{
  __shared__ char lds[131072];
  const int tid = threadIdx.x;
  const int wave = tid >> 6, lane = tid & 63;
  const int l16 = lane & 15, kq = lane >> 4;
  const int wr = wave >> 2, wc2 = wave & 3;

  const int nwg = gridDim.x;
  const int bid = blockIdx.x;
  const int qc = nwg >> 3, rc = nwg & 7;
  const int xcd = bid & 7;
  const int wgid = (xcd < rc ? xcd*(qc+1) : rc*(qc+1) + (xcd-rc)*qc) + (bid >> 3);
  const long brow = (long)(wgid / ntiles) * 256;
  const long bcol = (long)(wgid % ntiles) * 256;

  const int isbf = *flag;
  const __hip_bfloat16* Ause = isbf ? A_alt : A;
  const int nkt = K >> 6;

  const int srow = tid >> 3;
  const int schunk = tid & 7;
  const int wuni = wave << 10;

  auto stA = [&](int t, int buf, int issue) {
    int ar = issue*64 + srow;
    int cs = schunk ^ (ar & 7);
    long gr = brow + ar; if (gr > (long)M - 1) gr = M - 1;
    gload_lds16(Ause + gr*(long)K + t*64 + cs*8,
                lds + buf*65536 + issue*8192 + wuni);
  };
  auto stB = [&](int t, int buf, int issue) {
    int br = issue*64 + srow;
    int cs = schunk ^ (br & 7);
    gload_lds16(B + (bcol + br)*(long)K + t*64 + cs*8,
                lds + buf*65536 + 32768 + issue*8192 + wuni);
  };
  auto rdA = [&](int buf, int q, int a, int ks) -> s16x8 {
    int ar = wr*128 + q*32 + a*16 + l16;
    int ch = ks*4 + kq;
    return *(const s16x8*)(lds + buf*65536 + ar*128 + ((ch ^ (ar & 7)) << 4));
  };
  auto rdB = [&](int buf, int ni, int ks) -> s16x8 {
    int br = wc2*64 + ni*16 + l16;
    int ch = ks*4 + kq;
    return *(const s16x8*)(lds + buf*65536 + 32768 + br*128 + ((ch ^ (br & 7)) << 4));
  };

  f32x4 acc[8][4];
  #pragma unroll
  for (int i = 0; i < 8; ++i)
    #pragma unroll
    for (int j = 0; j < 4; ++j) acc[i][j] = (f32x4){0.f,0.f,0.f,0.f};

  stB(0,0,0); stB(0,0,1); stB(0,0,2); stB(0,0,3);
  stA(0,0,0); stA(0,0,2); stA(0,0,1); stA(0,0,3);
  asm volatile("s_waitcnt vmcnt(2)" ::: "memory");
  __builtin_amdgcn_s_barrier();

  for (int t = 0; t < nkt; ++t) {
    const int cur = t & 1, nxt = cur ^ 1;
    const bool pf = (t + 1 < nkt);
    s16x8 bfr[4][2], af[2][2];

    #pragma unroll
    for (int ni = 0; ni < 4; ++ni) { bfr[ni][0] = rdB(cur,ni,0); bfr[ni][1] = rdB(cur,ni,1); }
    af[0][0]=rdA(cur,0,0,0); af[0][1]=rdA(cur,0,0,1);
    af[1][0]=rdA(cur,0,1,0); af[1][1]=rdA(cur,0,1,1);
    if (pf) { stB(t+1,nxt,0); stB(t+1,nxt,1); }
    __builtin_amdgcn_s_barrier();
    asm volatile("s_waitcnt lgkmcnt(0)" ::: "memory");
    __builtin_amdgcn_sched_barrier(0);
    __builtin_amdgcn_s_setprio(1);
    #pragma unroll
    for (int ks = 0; ks < 2; ++ks)
      #pragma unroll
      for (int ni = 0; ni < 4; ++ni) {
        acc[0][ni] = __builtin_amdgcn_mfma_f32_16x16x32_bf16(af[0][ks], bfr[ni][ks], acc[0][ni], 0,0,0);
        acc[1][ni] = __builtin_amdgcn_mfma_f32_16x16x32_bf16(af[1][ks], bfr[ni][ks], acc[1][ni], 0,0,0);
      }
    __builtin_amdgcn_s_setprio(0);

    af[0][0]=rdA(cur,1,0,0); af[0][1]=rdA(cur,1,0,1);
    af[1][0]=rdA(cur,1,1,0); af[1][1]=rdA(cur,1,1,1);
    if (pf) {
      stB(t+1,nxt,2); stB(t+1,nxt,3);
      asm volatile("s_waitcnt vmcnt(4)" ::: "memory");
    } else {
      asm volatile("s_waitcnt vmcnt(0)" ::: "memory");
    }
    __builtin_amdgcn_s_barrier();
    asm volatile("s_waitcnt lgkmcnt(0)" ::: "memory");
    __builtin_amdgcn_sched_barrier(0);
    __builtin_amdgcn_s_setprio(1);
    #pragma unroll
    for (int ks = 0; ks < 2; ++ks)
      #pragma unroll
      for (int ni = 0; ni < 4; ++ni) {
        acc[2][ni] = __builtin_amdgcn_mfma_f32_16x16x32_bf16(af[0][ks], bfr[ni][ks], acc[2][ni], 0,0,0);
        acc[3][ni] = __builtin_amdgcn_mfma_f32_16x16x32_bf16(af[1][ks], bfr[ni][ks], acc[3][ni], 0,0,0);
      }
    __builtin_amdgcn_s_setprio(0);

    af[0][0]=rdA(cur,2,0,0); af[0][1]=rdA(cur,2,0,1);
    af[1][0]=rdA(cur,2,1,0); af[1][1]=rdA(cur,2,1,1);
    if (pf) { stA(t+1,nxt,0); stA(t+1,nxt,2); }
    __builtin_amdgcn_s_barrier();
    asm volatile("s_waitcnt lgkmcnt(0)" ::: "memory");
    __builtin_amdgcn_sched_barrier(0);
    __builtin_amdgcn_s_setprio(1);
    #pragma unroll
    for (int ks = 0; ks < 2; ++ks)
      #pragma unroll
      for (int ni = 0; ni < 4; ++ni) {
        acc[4][ni] = __builtin_amdgcn_mfma_f32_16x16x32_bf16(af[0][ks], bfr[ni][ks], acc[4][ni], 0,0,0);
        acc[5][ni] = __builtin_amdgcn_mfma_f32_16x16x32_bf16(af[1][ks], bfr[ni][ks], acc[5][ni], 0,0,0);
      }
    __builtin_amdgcn_s_setprio(0);

    af[0][0]=rdA(cur,3,0,0); af[0][1]=rdA(cur,3,0,1);
    af[1][0]=rdA(cur,3,1,0); af[1][1]=rdA(cur,3,1,1);
    if (pf) { stA(t+1,nxt,1); stA(t+1,nxt,3); }
    asm volatile("s_waitcnt vmcnt(2)" ::: "memory");
    __builtin_amdgcn_s_barrier();
    asm volatile("s_waitcnt lgkmcnt(0)" ::: "memory");
    __builtin_amdgcn_sched_barrier(0);
    __builtin_amdgcn_s_setprio(1);
    #pragma unroll
    for (int ks = 0; ks < 2; ++ks)
      #pragma unroll
      for (int ni = 0; ni < 4; ++ni) {
        acc[6][ni] = __builtin_amdgcn_mfma_f32_16x16x32_bf16(af[0][ks], bfr[ni][ks], acc[6][ni], 0,0,0);
        acc[7][ni] = __builtin_amdgcn_mfma_f32_16x16x32_bf16(af[1][ks], bfr[ni][ks], acc[7][ni], 0,0,0);
      }
    __builtin_amdgcn_s_setprio(0);
  }

  __builtin_amdgcn_s_barrier();

  const int f32o = flag_mode && (!isbf);
  float bv[4];
  #pragma unroll
  for (int ni = 0; ni < 4; ++ni) bv[ni] = bf2f(bias[bcol + wc2*64 + ni*16 + l16]);
  const int o4 = kq*4;

  if (!f32o) {
    __hip_bfloat16* eb = (__hip_bfloat16*)(lds + wave*2048);
    __hip_bfloat16* Cb = (__hip_bfloat16*)C;
    const int rr = lane >> 3, cg = lane & 7;
    #pragma unroll
    for (int mi = 0; mi < 8; ++mi) {
      #pragma unroll
      for (int ni = 0; ni < 4; ++ni)
        #pragma unroll
        for (int r = 0; r < 4; ++r) {
          const int row16 = o4 + r;
          const int sidx = row16*64 + ((((ni*2 + (l16 >> 3)) ^ (row16 & 7)) << 3) | (l16 & 7));
          eb[sidx] = f2bf(acc[mi][ni][r] + bv[ni]);
        }
      asm volatile("s_waitcnt lgkmcnt(0)" ::: "memory");
      __builtin_amdgcn_sched_barrier(0);
      #pragma unroll
      for (int pass = 0; pass < 2; ++pass) {
        const int row16 = pass*8 + rr;
        const long grow = brow + wr*128 + mi*16 + row16;
        if (grow < M) {
          s16x8 v = *(const s16x8*)(eb + row16*64 + ((cg ^ (row16 & 7)) << 3));
          *(s16x8*)(Cb + grow*(long)N + bcol + wc2*64 + cg*8) = v;
        }
      }
      asm volatile("s_waitcnt lgkmcnt(0)" ::: "memory");
      __builtin_amdgcn_sched_barrier(0);
    }
  } else {
    #pragma unroll
    for (int mi = 0; mi < 8; ++mi)
      #pragma unroll
      for (int ni = 0; ni < 4; ++ni)
        #pragma unroll
        for (int r = 0; r < 4; ++r) {
          const long grow = brow + wr*128 + mi*16 + o4 + r;
          if (grow < M)
            ((float*)C)[grow*(long)N + bcol + wc2*64 + ni*16 + l16] = acc[mi][ni][r] + bv[ni];
        }
  }
}

// ------- merged: out-proj GEMM (blocks < NGEMM_OP) + CLS split-K (blocks >= NGEMM_OP)
// GEMM path: C=d_out, A=xop, B=wOut, M=M_TOT, N=768, K=768, ntiles=3, flag_mode=1.
// CLS path: 512 threads, work guarded to tid<256 / wave<4; barriers uniform.
__global__ __launch_bounds__(512) void outproj_cls(
    const __hip_bfloat16* __restrict__ A,       // xop
    const __hip_bfloat16* __restrict__ B,       // wOut
    const __hip_bfloat16* __restrict__ bias,    // bOut
    void* __restrict__ C,                       // d_out
    const __hip_bfloat16* __restrict__ qkv,
    const __hip_bfloat16* __restrict__ mask,
    const __hip_bfloat16* __restrict__ mask_raw,
    const int* __restrict__ flag,
    const int* __restrict__ mzp,
    const int* __restrict__ top_idx,
    float* __restrict__ pO,
    float* __restrict__ pm,
    float* __restrict__ pl)
{
  __shared__ char lds[131072];
  const int tid = threadIdx.x;
  const int wave = tid >> 6, lane = tid & 63;
  const int l16 = lane & 15, kq = lane >> 4;
  const int isbf = *flag;

  if (blockIdx.x < NGEMM_OP) {
    // ================= out-proj GEMM path (verbatim schedule) =================
    const int wr = wave >> 2, wc2 = wave & 3;
    const int M = M_TOT, N = EDIM, K = EDIM, ntiles = 3;
    const int nwg = NGEMM_OP;
    const int bid = blockIdx.x;
    const int qc = nwg >> 3, rc = nwg & 7;
    const int xcd = bid & 7;
    const int wgid = (xcd < rc ? xcd*(qc+1) : rc*(qc+1) + (xcd-rc)*qc) + (bid >> 3);
    const long brow = (long)(wgid / ntiles) * 256;
    const long bcol = (long)(wgid % ntiles) * 256;
    const int nkt = K >> 6;

    const int srow = tid >> 3;
    const int schunk = tid & 7;
    const int wuni = wave << 10;

    auto stA = [&](int t, int buf, int issue) {
      int ar = issue*64 + srow;
      int cs = schunk ^ (ar & 7);
      long gr = brow + ar; if (gr > (long)M - 1) gr = M - 1;
      gload_lds16(A + gr*(long)K + t*64 + cs*8,
                  lds + buf*65536 + issue*8192 + wuni);
    };
    auto stB = [&](int t, int buf, int issue) {
      int br = issue*64 + srow;
      int cs = schunk ^ (br & 7);
      gload_lds16(B + (bcol + br)*(long)K + t*64 + cs*8,
                  lds + buf*65536 + 32768 + issue*8192 + wuni);
    };
    auto rdA = [&](int buf, int q, int a, int ks) -> s16x8 {
      int ar = wr*128 + q*32 + a*16 + l16;
      int ch = ks*4 + kq;
      return *(const s16x8*)(lds + buf*65536 + ar*128 + ((ch ^ (ar & 7)) << 4));
    };
    auto rdB = [&](int buf, int ni, int ks) -> s16x8 {
      int br = wc2*64 + ni*16 + l16;
      int ch = ks*4 + kq;
      return *(const s16x8*)(lds + buf*65536 + 32768 + br*128 + ((ch ^ (br & 7)) << 4));
    };

    f32x4 acc[8][4];
    #pragma unroll
    for (int i = 0; i < 8; ++i)
      #pragma unroll
      for (int j = 0; j < 4; ++j) acc[i][j] = (f32x4){0.f,0.f,0.f,0.f};

    stB(0,0,0); stB(0,0,1); stB(0,0,2); stB(0,0,3);
    stA(0,0,0); stA(0,0,2); stA(0,0,1); stA(0,0,3);
    asm volatile("s_waitcnt vmcnt(2)" ::: "memory");
    __builtin_amdgcn_s_barrier();

    for (int t = 0; t < nkt; ++t) {
      const int cur = t & 1, nxt = cur ^ 1;
      const bool pf = (t + 1 < nkt);
      s16x8 bfr[4][2], af[2][2];

      #pragma unroll
      for (int ni = 0; ni < 4; ++ni) { bfr[ni][0] = rdB(cur,ni,0); bfr[ni][1] = rdB(cur,ni,1); }
      af[0][0]=rdA(cur,0,0,0); af[0][1]=rdA(cur,0,0,1);
      af[1][0]=rdA(cur,0,1,0); af[1][1]=rdA(cur,0,1,1);
      if (pf) { stB(t+1,nxt,0); stB(t+1,nxt,1); }
      __builtin_amdgcn_s_barrier();
      asm volatile("s_waitcnt lgkmcnt(0)" ::: "memory");
      __builtin_amdgcn_sched_barrier(0);
      __builtin_amdgcn_s_setprio(1);
      #pragma unroll
      for (int ks = 0; ks < 2; ++ks)
        #pragma unroll
        for (int ni = 0; ni < 4; ++ni) {
          acc[0][ni] = __builtin_amdgcn_mfma_f32_16x16x32_bf16(af[0][ks], bfr[ni][ks], acc[0][ni], 0,0,0);
          acc[1][ni] = __builtin_amdgcn_mfma_f32_16x16x32_bf16(af[1][ks], bfr[ni][ks], acc[1][ni], 0,0,0);
        }
      __builtin_amdgcn_s_setprio(0);

      af[0][0]=rdA(cur,1,0,0); af[0][1]=rdA(cur,1,0,1);
      af[1][0]=rdA(cur,1,1,0); af[1][1]=rdA(cur,1,1,1);
      if (pf) {
        stB(t+1,nxt,2); stB(t+1,nxt,3);
        asm volatile("s_waitcnt vmcnt(4)" ::: "memory");
      } else {
        asm volatile("s_waitcnt vmcnt(0)" ::: "memory");
      }
      __builtin_amdgcn_s_barrier();
      asm volatile("s_waitcnt lgkmcnt(0)" ::: "memory");
      __builtin_amdgcn_sched_barrier(0);
      __builtin_amdgcn_s_setprio(1);
      #pragma unroll
      for (int ks = 0; ks < 2; ++ks)
        #pragma unroll
        for (int ni = 0; ni < 4; ++ni) {
          acc[2][ni] = __builtin_amdgcn_mfma_f32_16x16x32_bf16(af[0][ks], bfr[ni][ks], acc[2][ni], 0,0,0);
          acc[3][ni] = __builtin_amdgcn_mfma_f32_16x16x32_bf16(af[1][ks], bfr[ni][ks], acc[3][ni], 0,0,0);
        }
      __builtin_amdgcn_s_setprio(0);

      af[0][0]=rdA(cur,2,0,0); af[0][1]=rdA(cur,2,0,1);
      af[1][0]=rdA(cur,2,1,0); af[1][1]=rdA(cur,2,1,1);
      if (pf) { stA(t+1,nxt,0); stA(t+1,nxt,2); }
      __builtin_amdgcn_s_barrier();
      asm volatile("s_waitcnt lgkmcnt(0)" ::: "memory");
      __builtin_amdgcn_sched_barrier(0);
      __builtin_amdgcn_s_setprio(1);
      #pragma unroll
      for (int ks = 0; ks < 2; ++ks)
        #pragma unroll
        for (int ni = 0; ni < 4; ++ni) {
          acc[4][ni] = __builtin_amdgcn_mfma_f32_16x16x32_bf16(af[0][ks], bfr[ni][ks], acc[4][ni], 0,0,0);
          acc[5][ni] = __builtin_amdgcn_mfma_f32_16x16x32_bf16(af[1][ks], bfr[ni][ks], acc[5][ni], 0,0,0);
        }
      __builtin_amdgcn_s_setprio(0);

      af[0][0]=rdA(cur,3,0,0); af[0][1]=rdA(cur,3,0,1);
      af[1][0]=rdA(cur,3,1,0); af[1][1]=rdA(cur,3,1,1);
      if (pf) { stA(t+1,nxt,1); stA(t+1,nxt,3); }
      asm volatile("s_waitcnt vmcnt(2)" ::: "memory");
      __builtin_amdgcn_s_barrier();
      asm volatile("s_waitcnt lgkmcnt(0)" ::: "memory");
      __builtin_amdgcn_sched_barrier(0);
      __builtin_amdgcn_s_setprio(1);
      #pragma unroll
      for (int ks = 0; ks < 2; ++ks)
        #pragma unroll
        for (int ni = 0; ni < 4; ++ni) {
          acc[6][ni] = __builtin_amdgcn_mfma_f32_16x16x32_bf16(af[0][ks], bfr[ni][ks], acc[6][ni], 0,0,0);
          acc[7][ni] = __builtin_amdgcn_mfma_f32_16x16x32_bf16(af[1][ks], bfr[ni][ks], acc[7][ni], 0,0,0);
        }
      __builtin_amdgcn_s_setprio(0);
    }

    __builtin_amdgcn_s_barrier();

    float bv[4];
    #pragma unroll
    for (int ni = 0; ni < 4; ++ni) bv[ni] = bf2f(bias[bcol + wc2*64 + ni*16 + l16]);
    const int o4 = kq*4;

    if (isbf) {
      __hip_bfloat16* eb = (__hip_bfloat16*)(lds + wave*2048);
      __hip_bfloat16* Cb = (__hip_bfloat16*)C;
      const int rr = lane >> 3, cg = lane & 7;
      #pragma unroll
      for (int mi = 0; mi < 8; ++mi) {
        #pragma unroll
        for (int ni = 0; ni < 4; ++ni)
          #pragma unroll
          for (int r = 0; r < 4; ++r) {
            const int row16 = o4 + r;
            const int sidx = row16*64 + ((((ni*2 + (l16 >> 3)) ^ (row16 & 7)) << 3) | (l16 & 7));
            eb[sidx] = f2bf(acc[mi][ni][r] + bv[ni]);
          }
        asm volatile("s_waitcnt lgkmcnt(0)" ::: "memory");
        __builtin_amdgcn_sched_barrier(0);
        #pragma unroll
        for (int pass = 0; pass < 2; ++pass) {
          const int row16 = pass*8 + rr;
          const long grow = brow + wr*128 + mi*16 + row16;
          if (grow < M) {
            s16x8 v = *(const s16x8*)(eb + row16*64 + ((cg ^ (row16 & 7)) << 3));
            *(s16x8*)(Cb + grow*(long)N + bcol + wc2*64 + cg*8) = v;
          }
        }
        asm volatile("s_waitcnt lgkmcnt(0)" ::: "memory");
        __builtin_amdgcn_sched_barrier(0);
      }
    } else {
      #pragma unroll
      for (int mi = 0; mi < 8; ++mi)
        #pragma unroll
        for (int ni = 0; ni < 4; ++ni)
          #pragma unroll
          for (int r = 0; r < 4; ++r) {
            const long grow = brow + wr*128 + mi*16 + o4 + r;
            if (grow < M)
              ((float*)C)[grow*(long)N + bcol + wc2*64 + ni*16 + l16] = acc[mi][ni][r] + bv[ni];
          }
    }
  } else {
    // ================= CLS split-K path (512 threads; work in tid<256) =================
    __hip_bfloat16* lQ = (__hip_bfloat16*)lds;          // [16][64]    2048 B
    __hip_bfloat16* lS = lQ + 16*64;                    // [16][LSTR] 13568 B
    __hip_bfloat16* lV = lS + 16*LSTR;                  // [256][64]  32768 B
    float* red  = (float*)(lds + 49152);                // [16][17]
    float* rmax = (float*)(lds + 50304);                // [16]
    float* rsum = (float*)(lds + 50368);                // [16]

    const int cb = blockIdx.x - NGEMM_OP;
    const int sp = cb & 7;
    const int gh = cb >> 3;
    const int g = gh / NH;
    const int h = gh % NH;
    const int k0 = sp * KSPL;
    const int o4 = kq * 4;
    const int mz = *mzp;
    const __hip_bfloat16* msk = isbf ? mask_raw : mask;

    if (tid < 128) {
      int qi = tid >> 3, c8 = tid & 7;
      int ib = g*NF + qi;
      int top = top_idx[ib];
      f32x4 v = *(const f32x4*)(qkv + ((size_t)ib*TGT + top)*QKV_N + h*HD + c8*8);
      *(f32x4*)(lQ + qi*64 + c8*8) = v;
    }
    __syncthreads();

    if (wave < 4) {
      s16x8 q8[2];
      #pragma unroll
      for (int kk = 0; kk < 2; ++kk)
        q8[kk] = *(const s16x8*)(lQ + l16*64 + kk*32 + kq*8);

      for (int nf = wave; nf < 26; nf += 4) {
        const int keyl = nf*16 + l16;
        const int keyg = k0 + (keyl < KSPL ? keyl : 0);
        f32x4 a = {0.f,0.f,0.f,0.f};
        const size_t krow = (size_t)g*KG + keyg;
        #pragma unroll
        for (int kk = 0; kk < 2; ++kk) {
          s16x8 k8 = *(const s16x8*)(qkv + krow*QKV_N + EDIM + h*HD + kk*32 + kq*8);
          a = __builtin_amdgcn_mfma_f32_16x16x32_bf16(q8[kk], k8, a, 0, 0, 0);
        }
        float mval = 0.f;
        if (!mz && keyl < KSPL) {
          const int f = keyg / 197;
          const int t = keyg - f*197;
          mval = bf2f(msk[((size_t)(g*NF + f)*TGT + (TGT-1))*TGT + t]);
        }
        #pragma unroll
        for (int r = 0; r < 4; ++r)
          lS[(o4 + r)*LSTR + nf*16 + l16] = f2bf(keyl < KSPL ? a[r]*0.125f + mval : -1e30f);
      }
    }
    __syncthreads();

    // softmax (rows owned by tid<256)
    {
      const int q = tid >> 4, c = tid & 15;
      if (tid < 256) {
        float mx = -1e30f;
        for (int gch = c; gch < 52; gch += 16) {
          s16x8 sv = *(const s16x8*)(lS + q*LSTR + gch*8);
          #pragma unroll
          for (int j = 0; j < 8; ++j) mx = fmaxf(mx, b2f((unsigned short)sv[j]));
        }
        red[q*17 + c] = mx;
      }
      __syncthreads();
      if (tid < 16) {
        float m = red[tid*17];
        for (int j = 1; j < 16; ++j) m = fmaxf(m, red[tid*17 + j]);
        rmax[tid] = m;
      }
      __syncthreads();
      if (tid < 256) {
        const float rowmax = rmax[q];
        float sum = 0.f;
        for (int gch = c; gch < 52; gch += 16) {
          s16x8 sv = *(const s16x8*)(lS + q*LSTR + gch*8);
          s16x8 ov;
          #pragma unroll
          for (int jp = 0; jp < 4; ++jp) {
            float e0 = __expf(b2f((unsigned short)sv[2*jp])   - rowmax);
            float e1 = __expf(b2f((unsigned short)sv[2*jp+1]) - rowmax);
            sum += e0 + e1;
            unsigned int pr = packbf(e0, e1);
            ov[2*jp]   = (short)(pr & 0xffff);
            ov[2*jp+1] = (short)(pr >> 16);
          }
          *(s16x8*)(lS + q*LSTR + gch*8) = ov;
        }
        red[q*17 + c] = sum;
      }
      __syncthreads();
      if (tid < 16) {
        float s = 0.f;
        for (int j = 0; j < 16; ++j) s += red[tid*17 + j];
        rsum[tid] = s;
      }
    }

    // PV over 2 chunks; all 512 threads stage, tid<256 compute
    f32x4 oa = {0.f,0.f,0.f,0.f};
    const f32x4 z = {0.f,0.f,0.f,0.f};
    #pragma unroll
    for (int cki = 0; cki < 2; ++cki) {
      const int ck = cki * 256;
      const int nrows = cki ? 160 : 256;
      const int nks = cki ? 5 : 8;
      __syncthreads();
      for (int idx = tid; idx < nrows*8; idx += 512) {
        int t2 = idx >> 3, c8 = idx & 7;
        int keyl = ck + t2;
        f32x4 v = z;
        if (keyl < KSPL)
          v = *(const f32x4*)(qkv + ((size_t)g*KG + k0 + keyl)*QKV_N + 2*EDIM + h*HD + c8*8);
        *(f32x4*)(lV + swz(t2, c8*8)) = v;
      }
      __syncthreads();
      if (tid < 256) {
        for (int ks = 0; ks < nks; ++ks) {
          s16x8 pa = *(const s16x8*)(lS + l16*LSTR + ck + ks*32 + kq*8);
          s16x8 vf;
          #pragma unroll
          for (int j = 0; j < 8; ++j) {
            const int t2 = ks*32 + kq*8 + j;
            vf[j] = *(const short*)(lV + swz(t2, wave*16 + l16));
          }
          oa = __builtin_amdgcn_mfma_f32_16x16x32_bf16(pa, vf, oa, 0, 0, 0);
        }
      }
    }

    if (tid < 256) {
      const int ps = gh*NSPL + sp;
      #pragma unroll
      for (int r = 0; r < 4; ++r)
        pO[((size_t)ps*16 + (o4 + r))*64 + wave*16 + l16] = oa[r];
      if (tid < 16) {
        pm[ps*16 + tid] = rmax[tid];
        pl[ps*16 + tid] = rsum[tid];
      }
    }
  }
}

// ---------------- fused attention: V^T-only LDS, K direct from global ----------------
__global__ __launch_bounds__(256) void attn_fused(
    const __hip_bfloat16* __restrict__ qkv,
    const __hip_bfloat16* __restrict__ mask,
    const __hip_bfloat16* __restrict__ mask_raw,
    const int* __restrict__ flag,
    const int* __restrict__ mzp,
    __hip_bfloat16* __restrict__ xop)
{
  __shared__ __hip_bfloat16 lVt[64*VSTR];

  const int tid = threadIdx.x;
  const int blk = blockIdx.x;
  const int xcd = blk & 7;
  const int slot = blk >> 3;
  const int ih = xcd * 192 + (slot >> 2);
  const int qt = slot & 3;
  const int h = ih % NH;
  const int i = ih / NH;
  const int q0 = qt * 64;
  const size_t rowbase = (size_t)i * TGT;
  const int wave = tid >> 6, lane = tid & 63;
  const int l16 = lane & 15, kq = lane >> 4;
  const int mz = *mzp;
  const __hip_bfloat16* msk = (*flag) ? mask_raw : mask;

  int qr = q0 + wave*16 + l16;
  const int qrc = qr > TGT-1 ? TGT-1 : qr;
  s16x8 qf[2];
  #pragma unroll
  for (int kk = 0; kk < 2; ++kk)
    qf[kk] = *(const s16x8*)(qkv + (rowbase + qrc)*QKV_N + h*HD + kk*32 + kq*8);

  const f32x4 z = {0.f,0.f,0.f,0.f};
  for (int idx = tid; idx < 224*8; idx += 256) {
    int t = idx >> 3, c8 = idx & 7;
    f32x4 vv = z;
    if (t < TGT) vv = *(const f32x4*)(qkv + (rowbase + t)*QKV_N + 2*EDIM + h*HD + c8*8);
    const __hip_bfloat16* pv = (const __hip_bfloat16*)&vv;
    const int tx = t ^ (c8 << 3);
    #pragma unroll
    for (int j = 0; j < 8; ++j)
      lVt[(c8*8 + j)*VSTR + tx] = pv[j];
  }
  __syncthreads();

  f32x4 acc[14];
  #pragma unroll
  for (int nf = 0; nf < 14; ++nf) {
    int trow = nf*16 + l16; if (trow > TGT-1) trow = TGT-1;
    acc[nf] = (f32x4){0.f,0.f,0.f,0.f};
    #pragma unroll
    for (int kk = 0; kk < 2; ++kk) {
      s16x8 kf = *(const s16x8*)(qkv + (rowbase + trow)*QKV_N + EDIM + h*HD + kk*32 + kq*8);
      acc[nf] = __builtin_amdgcn_mfma_f32_16x16x32_bf16(kf, qf[kk], acc[nf], 0, 0, 0);
    }
  }

  float mx = -1e30f;
  #pragma unroll
  for (int nf = 0; nf < 14; ++nf) {
    #pragma unroll
    for (int r = 0; r < 4; ++r) {
      const int t = nf*16 + kq*4 + r;
      float s;
      if (t < TGT) {
        s = acc[nf][r]*0.125f;
        if (!mz) s += bf2f(msk[(rowbase + qrc)*TGT + t]);
      } else s = -1e30f;
      acc[nf][r] = s;
      mx = fmaxf(mx, s);
    }
  }
  mx = fmaxf(mx, __shfl_xor(mx, 16));
  mx = fmaxf(mx, __shfl_xor(mx, 32));

  float rs = 0.f;
  unsigned int pk[14][2];
  #pragma unroll
  for (int nf = 0; nf < 14; ++nf) {
    float p0 = __expf(acc[nf][0] - mx);
    float p1 = __expf(acc[nf][1] - mx);
    float p2 = __expf(acc[nf][2] - mx);
    float p3 = __expf(acc[nf][3] - mx);
    rs += (p0 + p1) + (p2 + p3);
    pk[nf][0] = packbf(p0, p1);
    pk[nf][1] = packbf(p2, p3);
  }
  rs += __shfl_xor(rs, 16);
  rs += __shfl_xor(rs, 32);

  f32x4 oacc[4];
  #pragma unroll
  for (int nf = 0; nf < 4; ++nf) oacc[nf] = (f32x4){0.f,0.f,0.f,0.f};

  const int slbase = l16 + ((kq & 1) << 5);
  #pragma unroll
  for (int kt = 0; kt < 7; ++kt) {
    s16x8 pa;
    #pragma unroll
    for (int jp = 0; jp < 4; ++jp) {
      const int srcLane = slbase + ((jp >> 1) << 4);
      int va = __shfl((int)pk[2*kt][jp & 1], srcLane, 64);
      int vb = __shfl((int)pk[2*kt + 1][jp & 1], srcLane, 64);
      int sel = (kq < 2) ? va : vb;
      pa[2*jp]     = (short)(sel & 0xffff);
      pa[2*jp + 1] = (short)(((unsigned int)sel) >> 16);
    }
    #pragma unroll
    for (int nf = 0; nf < 4; ++nf) {
      s16x8 vf = *(const s16x8*)(lVt + vswz(nf*16 + l16, kt*32 + kq*8));
      oacc[nf] = __builtin_amdgcn_mfma_f32_16x16x32_bf16(pa, vf, oacc[nf], 0, 0, 0);
    }
  }

  #pragma unroll
  for (int r = 0; r < 4; ++r) {
    const float rsrc = __shfl(rs, kq*4 + r, 64);
    const int qw = q0 + wave*16 + kq*4 + r;
    if (qw < TGT) {
      const float inv = 1.0f / rsrc;
      #pragma unroll
      for (int nf = 0; nf < 4; ++nf)
        xop[(rowbase + qw)*(size_t)EDIM + h*HD + nf*16 + l16] = f2bf(oacc[nf][r] * inv);
    }
  }
}

// ---------------- CLS combine: rescale partials, write x1b ----------------
__global__ __launch_bounds__(256) void cls_combine(
    const float* __restrict__ pO,
    const float* __restrict__ pm,
    const float* __restrict__ pl,
    __hip_bfloat16* __restrict__ x1buf)
{
  __shared__ float M[16];
  __shared__ float L[16];
  __shared__ float sc[NSPL][16];
  const int tid = threadIdx.x;
  const int gh = blockIdx.x;
  const int g = gh / NH;
  const int h = gh % NH;

  if (tid < 16) {
    float m = -1e30f;
    for (int s = 0; s < NSPL; ++s) m = fmaxf(m, pm[(gh*NSPL + s)*16 + tid]);
    M[tid] = m;
  }
  __syncthreads();
  if (tid < 128) {
    const int s = tid >> 4, q = tid & 15;
    sc[s][q] = __expf(pm[(gh*NSPL + s)*16 + q] - M[q]);
  }
  __syncthreads();
  if (tid < 16) {
    float l = 0.f;
    for (int s = 0; s < NSPL; ++s) l += pl[(gh*NSPL + s)*16 + tid] * sc[s][tid];
    L[tid] = l;
  }
  __syncthreads();
  for (int idx = tid; idx < 16*64; idx += 256) {
    const int q = idx >> 6, d = idx & 63;
    float acc = 0.f;
    for (int s = 0; s < NSPL; ++s)
      acc += pO[((size_t)(gh*NSPL + s)*16 + q)*64 + d] * sc[s][q];
    x1buf[((size_t)(g*NF + q))*EDIM + h*64 + d] = f2bf(acc / L[q]);
  }
}

// ---------------- LoRA head + CLS row update ----------------
__global__ __launch_bounds__(256) void final_update(
    void* __restrict__ out,
    const __hip_bfloat16* __restrict__ x1p,
    const __hip_bfloat16* __restrict__ dw, const __hip_bfloat16* __restrict__ db,
    const __hip_bfloat16* __restrict__ uw, const __hip_bfloat16* __restrict__ ub,
    const int* __restrict__ top_idx, const int* __restrict__ flag)
{
  __shared__ float x0[EDIM];
  __shared__ float hmid[64];
  const int i = blockIdx.x;
  const int tid = threadIdx.x;
  const int top = top_idx[i];
  const int isbf = *flag;
  const size_t rowoff = ((size_t)i*TGT + top)*EDIM;
  for (int e = tid; e < EDIM; e += 256)
    x0[e] = isbf ? bf2f(((const __hip_bfloat16*)out)[rowoff + e])
                 : ((const float*)out)[rowoff + e];
  __syncthreads();
  if (tid < 64) {
    float a = bf2f(db[tid]);
    for (int e = 0; e < EDIM; ++e) a += x0[e] * bf2f(dw[tid*EDIM + e]);
    hmid[tid] = a / (1.f + __expf(-1.702f * a));
  }
  __syncthreads();
  for (int e = tid; e < EDIM; e += 256) {
    float a = bf2f(ub[e]) + bf2f(x1p[(size_t)i*EDIM + e]);
    #pragma unroll
    for (int r = 0; r < 64; ++r) a += hmid[r] * bf2f(uw[e*64 + r]);
    if (isbf) ((__hip_bfloat16*)out)[rowoff + e] = f2bf(a);
    else ((float*)out)[rowoff + e] = a;
  }
}

extern "C" void kernel_launch(void* const* d_in, const int* in_sizes, int n_in,
                              void* d_out, int out_size, void* d_ws, size_t ws_size,
                              hipStream_t stream) {
  (void)in_sizes; (void)n_in; (void)out_size; (void)ws_size;
  const int* top_idx = (const int*)d_in[13];
  const __hip_bfloat16* x_raw    = (const __hip_bfloat16*)d_in[0];
  const __hip_bfloat16* mask_raw = (const __hip_bfloat16*)d_in[1];

  char* ws = (char*)d_ws;
  size_t off = 0;
  auto alloc = [&](size_t bytes) { char* p = ws + off; off += (bytes + 15) & ~(size_t)15; return p; };

  int* flag = (int*)alloc(16);
  int* mz   = (int*)alloc(16);
  __hip_bfloat16* x_c    = (__hip_bfloat16*)alloc((size_t)19365888*2);
  __hip_bfloat16* mask_c = (__hip_bfloat16*)alloc((size_t)4967552*2);
  __hip_bfloat16* wIn_c  = (__hip_bfloat16*)alloc((size_t)1769472*2);
  __hip_bfloat16* bIn_c  = (__hip_bfloat16*)alloc((size_t)2304*2);
  __hip_bfloat16* wOut_c = (__hip_bfloat16*)alloc((size_t)589824*2);
  __hip_bfloat16* bOut_c = (__hip_bfloat16*)alloc((size_t)768*2);
  __hip_bfloat16* la_c   = (__hip_bfloat16*)alloc((size_t)49152*2);
  __hip_bfloat16* lb_c   = (__hip_bfloat16*)alloc((size_t)147456*2);
  __hip_bfloat16* dw_c   = (__hip_bfloat16*)alloc((size_t)49152*2);
  __hip_bfloat16* db_c   = (__hip_bfloat16*)alloc((size_t)64*2);
  __hip_bfloat16* uw_c   = (__hip_bfloat16*)alloc((size_t)49152*2);
  __hip_bfloat16* ub_c   = (__hip_bfloat16*)alloc((size_t)768*2);
  __hip_bfloat16* Wc     = (__hip_bfloat16*)alloc((size_t)QKV_N*EDIM*2);
  __hip_bfloat16* qkv    = (__hip_bfloat16*)alloc((size_t)M_TOT*QKV_N*2);
  __hip_bfloat16* xop    = (__hip_bfloat16*)alloc((size_t)M_TOT*EDIM*2);
  __hip_bfloat16* x1b    = (__hip_bfloat16*)alloc((size_t)BSZ*EDIM*2);
  __hip_bfloat16* x1p    = (__hip_bfloat16*)alloc((size_t)BSZ*EDIM*2);
  float* pO = (float*)alloc((size_t)96*NSPL*16*64*4);
  float* pm = (float*)alloc((size_t)96*NSPL*16*4);
  float* pl = (float*)alloc((size_t)96*NSPL*16*4);

  detect_dtype<<<1, 64, 0, stream>>>((const unsigned short*)d_in[0], flag, mz);
  detect_mask_zero<<<2048, 256, 0, stream>>>((const unsigned int*)d_in[1], 4967552, flag, mz);

  convert_bf16<<<2048, 256, 0, stream>>>(d_in[0], x_c, 19365888/8, flag, 1);
  convert_bf16<<<2048, 256, 0, stream>>>(d_in[1], mask_c, 4967552/8, flag, 1);

  CvBatch cb;
  const int srcIdx[10] = {2,3,4,5,6,7,8,9,10,11};
  void* dsts[10] = {wIn_c, bIn_c, wOut_c, bOut_c, la_c, lb_c, dw_c, db_c, uw_c, ub_c};
  const int ns[10] = {1769472, 2304, 589824, 768, 49152, 147456, 49152, 64, 49152, 768};
  int cum = 0;
  for (int k = 0; k < 10; ++k) {
    cb.src[k] = d_in[srcIdx[k]];
    cb.dst[k] = dsts[k];
    cb.off8[k] = cum;
    cum += ns[k] / 8;
  }
  cb.off8[10] = cum;
  convert_batch<<<(cum + 255)/256, 256, 0, stream>>>(cb, flag);

  build_wc<<<2304, 256, 0, stream>>>(wIn_c, la_c, lb_c, Wc);

  gemm_bt_8ph<<<99*9, 512, 0, stream>>>(x_c, x_raw, Wc, bIn_c, qkv,
                                        M_TOT, QKV_N, EDIM, 9, flag, 0);
  attn_fused<<<dim3(6144), 256, 0, stream>>>(qkv, mask_c, mask_raw, flag, mz, xop);
  // merged: out-proj GEMM (297 blocks) + CLS split-K (768 blocks) in one grid
  outproj_cls<<<dim3(NGEMM_OP + 96*NSPL), 512, 0, stream>>>(
      xop, wOut_c, bOut_c, d_out,
      qkv, mask_c, mask_raw, flag, mz, top_idx, pO, pm, pl);
  cls_combine<<<dim3(96), 256, 0, stream>>>(pO, pm, pl, x1b);
  gemm_bt_8ph<<<3, 512, 0, stream>>>(x1b, x1b, wOut_c, bOut_c, x1p,
                                     BSZ, EDIM, EDIM, 3, flag, 0);
  final_update<<<128, 256, 0, stream>>>(d_out, x1p, dw_c, db_c, uw_c, ub_c, top_idx, flag);
}